// Round 7
// baseline (225.318 us; speedup 1.0000x reference)
//
#include <hip/hip_runtime.h>
#include <math.h>

#define LL    4096
#define CDIM  96
#define DIN   192
#define NST   16
#define XE    38   // dt_rank(6) + 2*16

typedef __attribute__((ext_vector_type(8))) short v8s;
typedef __attribute__((ext_vector_type(4))) float v4f;
typedef unsigned short ushort_t;
typedef unsigned int uint_t;

#if __has_builtin(__builtin_amdgcn_exp2f)
__device__ __forceinline__ float fexp2(float x) { return __builtin_amdgcn_exp2f(x); }
#else
__device__ __forceinline__ float fexp2(float x) { return exp2f(x); }
#endif
#if __has_builtin(__builtin_amdgcn_logf)
__device__ __forceinline__ float flog2(float x) { return __builtin_amdgcn_logf(x); }
#else
__device__ __forceinline__ float flog2(float x) { return __log2f(x); }
#endif

__device__ __forceinline__ float siluf(float x) {
    return x * __builtin_amdgcn_rcpf(1.f + fexp2(-1.44269504f * x));
}
__device__ __forceinline__ ushort_t f2bf(float f) {
    uint_t u = __builtin_bit_cast(uint_t, f);
    return (ushort_t)((u + 0x7fffu + ((u >> 16) & 1u)) >> 16);
}

// sum over 16-lane n-group via xor-shuffle (ds_swizzle pipe — pipelined, no VALU hazards)
__device__ __forceinline__ float rsum16(float v) {
    v += __shfl_xor(v, 1); v += __shfl_xor(v, 2);
    v += __shfl_xor(v, 4); v += __shfl_xor(v, 8);
    return v;
}

// ---------------- Kernel 1: merge proj(1x1) into dconv(3x3) -> Wbf[tap][co][ci] bf16
__global__ __launch_bounds__(256) void k_merge_w(const float* __restrict__ proj_w,
                                                 const float* __restrict__ dconv_w,
                                                 ushort_t* __restrict__ Wbf) {
    int idx = blockIdx.x * 256 + threadIdx.x;       // o*96*9 + c*9 + k
    if (idx >= 96 * 96 * 9) return;
    int k = idx % 9;
    int c = (idx / 9) % 96;
    int o = idx / (9 * 96);
    float s = 0.f;
    for (int i = 0; i < 192; ++i)
        s += dconv_w[(o * 192 + i) * 9 + k] * proj_w[i * 96 + c];
    Wbf[(k * 96 + o) * 96 + c] = f2bf(s);
}

// ---------------- Kernel 1b: all weight f32->bf16 conversions in one launch
__global__ __launch_bounds__(256) void k_cvt_all(const float* __restrict__ in_proj_w,
                                                 const float* __restrict__ out_proj_w,
                                                 const float* __restrict__ x_proj_w,
                                                 ushort_t* __restrict__ Wibf,
                                                 ushort_t* __restrict__ Wobf,
                                                 ushort_t* __restrict__ Wxbf) {
    int i = blockIdx.x * 256 + threadIdx.x;
    if (i < 36864) { Wibf[i] = f2bf(in_proj_w[i]); return; }
    i -= 36864;
    if (i < 18432) { Wobf[i] = f2bf(out_proj_w[i]); return; }
    i -= 18432;
    if (i < 9216) {
        int e = i / 192;
        Wxbf[i] = (e < XE) ? f2bf(x_proj_w[i]) : (ushort_t)0;
    }
}

// ---------------- Kernel 2a: x (B,96,64,64) f32 -> xT[b][66][68][96] bf16, zero halo
__global__ __launch_bounds__(256) void k_xpad(const float* __restrict__ x,
                                              ushort_t* __restrict__ xT) {
    int yy = blockIdx.x;        // 0..65
    int b  = blockIdx.y;
    int yv = yy - 1;
    for (int i = threadIdx.x; i < 68 * 12; i += 256) {
        int xx = i % 68, cig = i / 68;
        int xv = xx - 1;
        ushort_t u[8];
        if (yv >= 0 && yv < 64 && xv >= 0 && xv < 64) {
            const float* sp = x + ((size_t)(b * 96 + cig * 8)) * LL + yv * 64 + xv;
#pragma unroll
            for (int j = 0; j < 8; ++j) u[j] = f2bf(sp[j * LL]);
        } else {
#pragma unroll
            for (int j = 0; j < 8; ++j) u[j] = 0;
        }
        uint4 pk;
        pk.x = u[0] | ((uint_t)u[1] << 16); pk.y = u[2] | ((uint_t)u[3] << 16);
        pk.z = u[4] | ((uint_t)u[5] << 16); pk.w = u[6] | ((uint_t)u[7] << 16);
        *(uint4*)(xT + (((size_t)b * 66 + yy) * 68 + xx) * 96 + cig * 8) = pk;
    }
}

// ---------------- Kernel 2b: implicit-GEMM 3x3 conv via MFMA bf16 -> seqT[b][l][c] bf16
__global__ __launch_bounds__(384, 2) void k_conv_mfma(const ushort_t* __restrict__ xT,
                                                      const ushort_t* __restrict__ Wbf,
                                                      ushort_t* __restrict__ seqT) {
    int tid = threadIdx.x;
    int w = tid >> 6, l = tid & 63;
    int n = l & 15, g = l >> 4;
    int blk = blockIdx.x;
    int b = blk >> 7, rem = blk & 127;
    int y = rem >> 1, half = rem & 1;
    int x0 = (half * 2 + (w & 1)) * 16;
    int co0 = (w >> 1) * 32;
    v4f acc0 = {0.f, 0.f, 0.f, 0.f};
    v4f acc1 = {0.f, 0.f, 0.f, 0.f};
    const ushort_t* xb = xT + (((size_t)b * 66 + y) * 68 + x0 + n) * 96 + g * 8;
    const ushort_t* aw = Wbf + ((size_t)co0 + n) * 96 + g * 8;
#pragma unroll
    for (int tap = 0; tap < 9; ++tap) {
        int dy = tap / 3, dx = tap % 3;
        const ushort_t* bp = xb + (dy * 68 + dx) * 96;
        const ushort_t* ap = aw + (size_t)tap * 96 * 96;
#pragma unroll
        for (int kk = 0; kk < 3; ++kk) {
            v8s bf = *(const v8s*)(bp + kk * 32);
            v8s a0 = *(const v8s*)(ap + kk * 32);
            v8s a1 = *(const v8s*)(ap + 16 * 96 + kk * 32);
            acc0 = __builtin_amdgcn_mfma_f32_16x16x32_bf16(a0, bf, acc0, 0, 0, 0);
            acc1 = __builtin_amdgcn_mfma_f32_16x16x32_bf16(a1, bf, acc1, 0, 0, 0);
        }
    }
    size_t sb = ((size_t)b * 4096 + y * 64 + x0 + n) * 96;
    ushort4 p0, p1;
    p0.x = f2bf(acc0[0]); p0.y = f2bf(acc0[1]); p0.z = f2bf(acc0[2]); p0.w = f2bf(acc0[3]);
    p1.x = f2bf(acc1[0]); p1.y = f2bf(acc1[1]); p1.z = f2bf(acc1[2]); p1.w = f2bf(acc1[3]);
    *(ushort4*)(seqT + sb + co0 + g * 4) = p0;
    *(ushort4*)(seqT + sb + co0 + 16 + g * 4) = p1;
}

// ---------------- Kernel 3: in_proj via MFMA -> xz[b][e][l] f32
__global__ __launch_bounds__(256, 3) void k_inproj(const ushort_t* __restrict__ seqT,
                                                   const ushort_t* __restrict__ Wibf,
                                                   float* __restrict__ xz) {
    int tid = threadIdx.x;
    int w = tid >> 6, l = tid & 63;
    int n = l & 15, g = l >> 4;
    int blk = blockIdx.x;
    int b = blk >> 8;
    int l0 = (blk & 255) * 16;
    int coh = w * 96;
    v4f acc[6];
#pragma unroll
    for (int mt = 0; mt < 6; ++mt) acc[mt] = (v4f){0.f, 0.f, 0.f, 0.f};
    const ushort_t* bp = seqT + ((size_t)b * 4096 + l0 + n) * 96 + g * 8;
    const ushort_t* ap = Wibf + ((size_t)coh + n) * 96 + g * 8;
#pragma unroll
    for (int kk = 0; kk < 3; ++kk) {
        v8s bf = *(const v8s*)(bp + kk * 32);
#pragma unroll
        for (int mt = 0; mt < 6; ++mt) {
            v8s af = *(const v8s*)(ap + mt * 16 * 96 + kk * 32);
            acc[mt] = __builtin_amdgcn_mfma_f32_16x16x32_bf16(af, bf, acc[mt], 0, 0, 0);
        }
    }
    float* ob = xz + (size_t)b * 384 * LL + l0 + n;
#pragma unroll
    for (int mt = 0; mt < 6; ++mt) {
        int e = coh + mt * 16 + g * 4;
#pragma unroll
        for (int r = 0; r < 4; ++r)
            ob[(size_t)(e + r) * LL] = acc[mt][r];
    }
}

// ---------------- Kernel 4: causal depthwise conv1d (k=4) + SiLU -> xc f32 + xcT bf16
__global__ __launch_bounds__(256) void k_conv1d(const float* __restrict__ xz,
                                                const float* __restrict__ w,
                                                const float* __restrict__ bias,
                                                float* __restrict__ xc,
                                                ushort_t* __restrict__ xcT) {
    int tid = blockIdx.x * 256 + threadIdx.x;   // B*192*1024 threads
    int tq = tid & 1023;
    int bd = tid >> 10;
    int d = bd % DIN, b = bd / DIN;
    const float* xin = xz + (size_t)(b * 384 + d) * LL;
    int t0 = tq * 4;
    float4 cur = *(const float4*)(xin + t0);
    float pm3 = 0.f, pm2 = 0.f, pm1 = 0.f;
    if (t0 > 0) {
        float4 prev = *(const float4*)(xin + t0 - 4);
        pm3 = prev.y; pm2 = prev.z; pm1 = prev.w;
    }
    float in[7] = {pm3, pm2, pm1, cur.x, cur.y, cur.z, cur.w};
    float w0 = w[d * 4 + 0], w1 = w[d * 4 + 1], w2 = w[d * 4 + 2], w3 = w[d * 4 + 3];
    float bb = bias[d];
    float o[4];
#pragma unroll
    for (int i = 0; i < 4; ++i) {
        float s = bb + w0 * in[i] + w1 * in[i + 1] + w2 * in[i + 2] + w3 * in[i + 3];
        o[i] = siluf(s);
    }
    float4 ov; ov.x = o[0]; ov.y = o[1]; ov.z = o[2]; ov.w = o[3];
    *(float4*)(xc + (size_t)(b * DIN + d) * LL + t0) = ov;
    ushort_t* xt = xcT + ((size_t)b * 4096 + t0) * DIN + d;
#pragma unroll
    for (int i = 0; i < 4; ++i)
        xt[(size_t)i * DIN] = f2bf(o[i]);
}

// ---------------- Kernel 5: x_proj via MFMA, epilogue scatters to dtT/Bt/Ct [e][t] f32
__global__ __launch_bounds__(256, 4) void k_xprojm(const ushort_t* __restrict__ xcT,
                                                   const ushort_t* __restrict__ Wxbf,
                                                   float* __restrict__ dtT,
                                                   float* __restrict__ Bt,
                                                   float* __restrict__ Ct) {
    int tid = threadIdx.x;
    int w = tid >> 6, l = tid & 63;
    int n = l & 15, g = l >> 4;
    int b = blockIdx.y;
    int l0 = blockIdx.x * 64 + w * 16;
    const ushort_t* bp = xcT + ((size_t)b * 4096 + l0 + n) * 192 + g * 8;
    const ushort_t* ap = Wxbf + (size_t)n * 192 + g * 8;
    v4f acc[3];
#pragma unroll
    for (int m = 0; m < 3; ++m) acc[m] = (v4f){0.f, 0.f, 0.f, 0.f};
#pragma unroll
    for (int kk = 0; kk < 6; ++kk) {
        v8s bf = *(const v8s*)(bp + kk * 32);
#pragma unroll
        for (int m = 0; m < 3; ++m) {
            v8s af = *(const v8s*)(ap + m * 16 * 192 + kk * 32);
            acc[m] = __builtin_amdgcn_mfma_f32_16x16x32_bf16(af, bf, acc[m], 0, 0, 0);
        }
    }
    float* dtb = dtT + (size_t)b * 6 * LL + l0 + n;
    float* Btb = Bt + (size_t)b * NST * LL + l0 + n;
    float* Ctb = Ct + (size_t)b * NST * LL + l0 + n;
#pragma unroll
    for (int m = 0; m < 3; ++m)
#pragma unroll
        for (int r = 0; r < 4; ++r) {
            int e = m * 16 + g * 4 + r;
            float v = acc[m][r];
            if (e < 6)       dtb[(size_t)e * LL] = v;
            else if (e < 22) Btb[(size_t)(e - 6) * LL] = v;
            else if (e < 38) Ctb[(size_t)(e - 22) * LL] = v;
        }
}

// ---------------- Kernel 6: dt_proj + softplus -> delta (B,192,L); reads dtT [r][t]
__global__ __launch_bounds__(256) void k_dtproj(const float* __restrict__ dtT,
                                                const float* __restrict__ dtw,
                                                const float* __restrict__ dtb,
                                                float* __restrict__ delta) {
    int tx = threadIdx.x, ty = threadIdx.y;   // (64,4)
    int b = blockIdx.y;
    int l = blockIdx.x * 64 + tx;
    int d0 = blockIdx.z * 48 + ty * 12;
    const float* dbase = dtT + (size_t)b * 6 * LL + l;
    float r0 = dbase[0], r1 = dbase[LL], r2 = dbase[2 * LL];
    float r3 = dbase[3 * LL], r4 = dbase[4 * LL], r5 = dbase[5 * LL];
#pragma unroll
    for (int j = 0; j < 12; ++j) {
        int dd = d0 + j;
        const float* wr2 = dtw + dd * 6;
        float s = dtb[dd] + wr2[0] * r0 + wr2[1] * r1 + wr2[2] * r2
                          + wr2[3] * r3 + wr2[4] * r4 + wr2[5] * r5;
        float e = fexp2(s * 1.44269504f);
        float sp = 0.69314718f * flog2(1.f + e);
        delta[((size_t)b * DIN + dd) * LL + l] = sp;
    }
}

// ---------------- Kernel 7: chunked selective scan + gate -> ygT bf16 (aliased on xz)
#define SC_STEP(DU, UU, BV)                                              \
    {                                                                    \
        float a0 = fexp2((DU).x * A2);                                   \
        float a1 = fexp2((DU).y * A2);                                   \
        float a2 = fexp2((DU).z * A2);                                   \
        float a3 = fexp2((DU).w * A2);                                   \
        h = fmaf(a0, h, (DU).x * (UU).x * (BV).x);                       \
        h = fmaf(a1, h, (DU).y * (UU).y * (BV).y);                       \
        h = fmaf(a2, h, (DU).z * (UU).z * (BV).z);                       \
        h = fmaf(a3, h, (DU).w * (UU).w * (BV).w);                       \
        aP *= (a0 * a1) * (a2 * a3);                                     \
    }

#define SC_PSTEP(S, DU, UU, BV, CV, ZZ)                                  \
    {                                                                    \
        float a0 = fexp2((DU).x * A2);                                   \
        float a1 = fexp2((DU).y * A2);                                   \
        float a2 = fexp2((DU).z * A2);                                   \
        float a3 = fexp2((DU).w * A2);                                   \
        h = fmaf(a0, h, (DU).x * (UU).x * (BV).x); float p0 = h * (CV).x; \
        h = fmaf(a1, h, (DU).y * (UU).y * (BV).y); float p1 = h * (CV).y; \
        h = fmaf(a2, h, (DU).z * (UU).z * (BV).z); float p2 = h * (CV).z; \
        h = fmaf(a3, h, (DU).w * (UU).w * (BV).w); float p3 = h * (CV).w; \
        p0 = rsum16(p0); p1 = rsum16(p1);                                \
        p2 = rsum16(p2); p3 = rsum16(p3);                                \
        float y0 = fmaf(Dd, (UU).x, p0) * siluf((ZZ).x);                 \
        float y1 = fmaf(Dd, (UU).y, p1) * siluf((ZZ).y);                 \
        float y2 = fmaf(Dd, (UU).z, p2) * siluf((ZZ).z);                 \
        float y3 = fmaf(Dd, (UU).w, p3) * siluf((ZZ).w);                 \
        if (n == 0) {                                                    \
            size_t tb_ = (size_t)(t0 + (S) * 4) * DIN + d;               \
            ygb[tb_]           = f2bf(y0);                               \
            ygb[tb_ + DIN]     = f2bf(y1);                               \
            ygb[tb_ + 2 * DIN] = f2bf(y2);                               \
            ygb[tb_ + 3 * DIN] = f2bf(y3);                               \
        }                                                                \
    }

__global__ __launch_bounds__(512, 8) void k_scan(const float* __restrict__ delta,
                                                 const float* __restrict__ xc,
                                                 const float* __restrict__ Bt,
                                                 const float* __restrict__ Ct,
                                                 const float* __restrict__ A_log,
                                                 const float* __restrict__ Dp,
                                                 float* __restrict__ xz) {
    __shared__ float s_d[32 * 132];       // chunk c at c*132 (+4 pad)
    __shared__ float s_u[32 * 132];
    __shared__ float s_a[32][17];
    __shared__ float s_h[32][17];
    int tid = threadIdx.x;
    int n = tid & 15, cg = tid >> 4;      // 32 chunks x 16 states
    int bd = blockIdx.x;
    int d = bd % DIN, b = bd / DIN;
    const float* drow = delta + (size_t)(b * DIN + d) * LL;
    const float* urow = xc    + (size_t)(b * DIN + d) * LL;
    const float* zrow = xz    + (size_t)(b * 384 + DIN + d) * LL;
    ushort_t* ygb     = (ushort_t*)(xz + (size_t)b * 384 * LL);
    float A2 = -__expf(A_log[d * NST + n]) * 1.44269504f;   // for fexp2
    float Dd = Dp[d];

    {
        int t8 = tid * 8;
        int li = ((t8 >> 7) * 132) + (t8 & 127);
        *(float4*)&s_d[li]     = *(const float4*)(drow + t8);
        *(float4*)&s_d[li + 4] = *(const float4*)(drow + t8 + 4);
        *(float4*)&s_u[li]     = *(const float4*)(urow + t8);
        *(float4*)&s_u[li + 4] = *(const float4*)(urow + t8 + 4);
    }
    __syncthreads();

    int t0 = cg * 128;
    int lb = cg * 132;
    const float* pB = Bt + ((size_t)b * NST + n) * LL + t0;
    const float* pC = Ct + ((size_t)b * NST + n) * LL + t0;

    // ---- phase 1: per-chunk aggregates, float4-pipelined
    float h = 0.f, aP = 1.f;
    float4 du_c = *(float4*)&s_d[lb];
    float4 u_c  = *(float4*)&s_u[lb];
    float4 B_c  = *(const float4*)pB;
    for (int s = 0; s < 31; ++s) {
        int ln = lb + s * 4 + 4;
        float4 du_n = *(float4*)&s_d[ln];
        float4 u_n  = *(float4*)&s_u[ln];
        float4 B_n  = *(const float4*)(pB + s * 4 + 4);
        SC_STEP(du_c, u_c, B_c);
        du_c = du_n; u_c = u_n; B_c = B_n;
    }
    SC_STEP(du_c, u_c, B_c);
    s_a[cg][n] = aP;
    s_h[cg][n] = h;
    __syncthreads();

    // ---- phase 2: Kogge-Stone scan of 32 chunk aggregates (per n)
    {
        int l = tid & 63, w = tid >> 6;
        int c = l & 31, nn = (w << 1) | (l >> 5);
        float a  = s_a[c][nn];
        float hh = s_h[c][nn];
#pragma unroll
        for (int st = 1; st < 32; st <<= 1) {
            float ap = __shfl_up(a, st, 32);
            float hp = __shfl_up(hh, st, 32);
            bool ok = (c >= st);
            hh = ok ? fmaf(a, hp, hh) : hh;
            a  = ok ? a * ap : a;
        }
        float h0 = __shfl_up(hh, 1, 32);
        if (c == 0) h0 = 0.f;
        s_a[c][nn] = h0;
    }
    __syncthreads();

    // ---- phase 3: recompute with correct h0; shuffle-reduce over n; gate; store
    h = s_a[cg][n];
    du_c = *(float4*)&s_d[lb];
    u_c  = *(float4*)&s_u[lb];
    B_c  = *(const float4*)pB;
    float4 C_c = *(const float4*)pC;
    float4 z_c = *(const float4*)(zrow + t0);
    for (int s = 0; s < 31; ++s) {
        int ln = lb + s * 4 + 4;
        float4 du_n = *(float4*)&s_d[ln];
        float4 u_n  = *(float4*)&s_u[ln];
        float4 B_n  = *(const float4*)(pB + s * 4 + 4);
        float4 C_n  = *(const float4*)(pC + s * 4 + 4);
        float4 z_n  = *(const float4*)(zrow + t0 + s * 4 + 4);
        SC_PSTEP(s, du_c, u_c, B_c, C_c, z_c);
        du_c = du_n; u_c = u_n; B_c = B_n; C_c = C_n; z_c = z_n;
    }
    SC_PSTEP(31, du_c, u_c, B_c, C_c, z_c);
}

// ---------------- Kernel 8: out_proj via MFMA: out[b][c][l] f32 = W[c][d] * ygT[l][d]
__global__ __launch_bounds__(512, 2) void k_outproj(const float* __restrict__ xzBase,
                                                    const ushort_t* __restrict__ Wobf,
                                                    float* __restrict__ out) {
    int tid = threadIdx.x;
    int w = tid >> 6, l = tid & 63;
    int n = l & 15, g = l >> 4;
    int b = blockIdx.y;
    int l0 = blockIdx.x * 64 + (w >> 1) * 16;
    int c0 = (w & 1) * 48;
    const ushort_t* ygb = (const ushort_t*)(xzBase + (size_t)b * 384 * LL);
    const ushort_t* bp = ygb + ((size_t)l0 + n) * 192 + g * 8;
    const ushort_t* ap = Wobf + ((size_t)c0 + n) * 192 + g * 8;
    v4f acc[3];
#pragma unroll
    for (int m = 0; m < 3; ++m) acc[m] = (v4f){0.f, 0.f, 0.f, 0.f};
#pragma unroll
    for (int kk = 0; kk < 6; ++kk) {
        v8s bf = *(const v8s*)(bp + kk * 32);
#pragma unroll
        for (int m = 0; m < 3; ++m) {
            v8s af = *(const v8s*)(ap + m * 16 * 192 + kk * 32);
            acc[m] = __builtin_amdgcn_mfma_f32_16x16x32_bf16(af, bf, acc[m], 0, 0, 0);
        }
    }
    float* ob = out + (size_t)b * 96 * LL + l0 + n;
#pragma unroll
    for (int m = 0; m < 3; ++m)
#pragma unroll
        for (int r = 0; r < 4; ++r)
            ob[(size_t)(c0 + m * 16 + g * 4 + r) * LL] = acc[m][r];
}

extern "C" void kernel_launch(void* const* d_in, const int* in_sizes, int n_in,
                              void* d_out, int out_size, void* d_ws, size_t ws_size,
                              hipStream_t stream) {
    const float* x         = (const float*)d_in[0];
    const float* proj_w    = (const float*)d_in[1];
    const float* dconv_w   = (const float*)d_in[2];
    const float* in_proj_w = (const float*)d_in[3];
    const float* conv1d_w  = (const float*)d_in[4];
    const float* conv1d_b  = (const float*)d_in[5];
    const float* x_proj_w  = (const float*)d_in[6];
    const float* dt_proj_w = (const float*)d_in[7];
    const float* dt_proj_b = (const float*)d_in[8];
    const float* A_log     = (const float*)d_in[9];
    const float* Dp        = (const float*)d_in[10];
    const float* out_proj_w= (const float*)d_in[11];
    float* out = (float*)d_out;
    float* ws  = (float*)d_ws;

    // carve (float units)
    ushort_t* Wbf  = (ushort_t*)ws;                      // 82,944 sh -> 41,472 fl
    ushort_t* Wibf = (ushort_t*)(ws + 41472);            // 36,864 sh -> 18,432 fl
    ushort_t* Wobf = (ushort_t*)(ws + 59904);            // 18,432 sh ->  9,216 fl
    ushort_t* Wxbf = (ushort_t*)(ws + 69120);            //  9,216 sh ->  4,608 fl
    ushort_t* xT   = (ushort_t*)(ws + 73728);            // 1,723,392 sh -> 861,696 fl
    ushort_t* seqT = (ushort_t*)(ws + 935424);           // 1,572,864 sh -> 786,432 fl
    float* xz   = ws + 1721856;                          // 4*384*4096 = 6,291,456
    float* xc   = xz + 6291456;                          // 3,145,728
    float* dtT  = xc + 3145728;                          // 4*6*4096   =    98,304
    float* Bt   = dtT + 98304;                           // 4*16*4096  =   262,144
    float* Ct   = Bt + 262144;                           // 4*16*4096  =   262,144
    float* delta= Ct + 262144;                           // 3,145,728
    ushort_t* xcT = (ushort_t*)delta;                    // alias: dead once delta written
    // ygT aliases xz lower half per-batch (xin dead after conv1d)

    k_merge_w<<<dim3(324), dim3(256), 0, stream>>>(proj_w, dconv_w, Wbf);
    k_cvt_all<<<dim3(252), dim3(256), 0, stream>>>(in_proj_w, out_proj_w, x_proj_w,
                                                   Wibf, Wobf, Wxbf);
    k_xpad<<<dim3(66, 4), dim3(256), 0, stream>>>(x, xT);
    k_conv_mfma<<<dim3(512), dim3(384), 0, stream>>>(xT, Wbf, seqT);
    k_inproj<<<dim3(1024), dim3(256), 0, stream>>>(seqT, Wibf, xz);
    k_conv1d<<<dim3(3072), dim3(256), 0, stream>>>(xz, conv1d_w, conv1d_b, xc, xcT);
    k_xprojm<<<dim3(64, 4), dim3(256), 0, stream>>>(xcT, Wxbf, dtT, Bt, Ct);
    k_dtproj<<<dim3(64, 4, 4), dim3(64, 4), 0, stream>>>(dtT, dt_proj_w, dt_proj_b, delta);
    k_scan<<<dim3(768), dim3(512), 0, stream>>>(delta, xc, Bt, Ct, A_log, Dp, xz);
    k_outproj<<<dim3(64, 4), dim3(512), 0, stream>>>(xz, Wobf, out);
}

// Round 8
// 151.634 us; speedup vs baseline: 1.4859x; 1.4859x over previous
//
#include <hip/hip_runtime.h>
#include <math.h>

#define LL    4096
#define CDIM  96
#define DIN   192
#define NST   16
#define XE    38   // dt_rank(6) + 2*16

typedef __attribute__((ext_vector_type(8))) short v8s;
typedef __attribute__((ext_vector_type(4))) float v4f;
typedef unsigned short ushort_t;
typedef unsigned int uint_t;

#if __has_builtin(__builtin_amdgcn_exp2f)
__device__ __forceinline__ float fexp2(float x) { return __builtin_amdgcn_exp2f(x); }
#else
__device__ __forceinline__ float fexp2(float x) { return exp2f(x); }
#endif
#if __has_builtin(__builtin_amdgcn_logf)
__device__ __forceinline__ float flog2(float x) { return __builtin_amdgcn_logf(x); }
#else
__device__ __forceinline__ float flog2(float x) { return __log2f(x); }
#endif

__device__ __forceinline__ float siluf(float x) {
    return x * __builtin_amdgcn_rcpf(1.f + fexp2(-1.44269504f * x));
}
__device__ __forceinline__ ushort_t f2bf(float f) {
    uint_t u = __builtin_bit_cast(uint_t, f);
    return (ushort_t)((u + 0x7fffu + ((u >> 16) & 1u)) >> 16);
}

// sum over 16-lane n-group via xor-shuffle
__device__ __forceinline__ float rsum16(float v) {
    v += __shfl_xor(v, 1); v += __shfl_xor(v, 2);
    v += __shfl_xor(v, 4); v += __shfl_xor(v, 8);
    return v;
}

// ---------------- Kernel 1: merge proj(1x1) into dconv(3x3) -> Wbf[tap][co][ci] bf16
__global__ __launch_bounds__(256) void k_merge_w(const float* __restrict__ proj_w,
                                                 const float* __restrict__ dconv_w,
                                                 ushort_t* __restrict__ Wbf) {
    int idx = blockIdx.x * 256 + threadIdx.x;       // o*96*9 + c*9 + k
    if (idx >= 96 * 96 * 9) return;
    int k = idx % 9;
    int c = (idx / 9) % 96;
    int o = idx / (9 * 96);
    float s = 0.f;
    for (int i = 0; i < 192; ++i)
        s += dconv_w[(o * 192 + i) * 9 + k] * proj_w[i * 96 + c];
    Wbf[(k * 96 + o) * 96 + c] = f2bf(s);
}

// ---------------- Kernel 1b: all weight f32->bf16 conversions in one launch
__global__ __launch_bounds__(256) void k_cvt_all(const float* __restrict__ in_proj_w,
                                                 const float* __restrict__ out_proj_w,
                                                 const float* __restrict__ x_proj_w,
                                                 ushort_t* __restrict__ Wibf,
                                                 ushort_t* __restrict__ Wobf,
                                                 ushort_t* __restrict__ Wxbf) {
    int i = blockIdx.x * 256 + threadIdx.x;
    if (i < 36864) { Wibf[i] = f2bf(in_proj_w[i]); return; }
    i -= 36864;
    if (i < 18432) { Wobf[i] = f2bf(out_proj_w[i]); return; }
    i -= 18432;
    if (i < 9216) {
        int e = i / 192;
        Wxbf[i] = (e < XE) ? f2bf(x_proj_w[i]) : (ushort_t)0;
    }
}

// ---------------- Kernel 2a: x (B,96,64,64) f32 -> xT[b][66][68][96] bf16, zero halo
__global__ __launch_bounds__(256) void k_xpad(const float* __restrict__ x,
                                              ushort_t* __restrict__ xT) {
    int yy = blockIdx.x;        // 0..65
    int b  = blockIdx.y;
    int yv = yy - 1;
    for (int i = threadIdx.x; i < 68 * 12; i += 256) {
        int xx = i % 68, cig = i / 68;
        int xv = xx - 1;
        ushort_t u[8];
        if (yv >= 0 && yv < 64 && xv >= 0 && xv < 64) {
            const float* sp = x + ((size_t)(b * 96 + cig * 8)) * LL + yv * 64 + xv;
#pragma unroll
            for (int j = 0; j < 8; ++j) u[j] = f2bf(sp[j * LL]);
        } else {
#pragma unroll
            for (int j = 0; j < 8; ++j) u[j] = 0;
        }
        uint4 pk;
        pk.x = u[0] | ((uint_t)u[1] << 16); pk.y = u[2] | ((uint_t)u[3] << 16);
        pk.z = u[4] | ((uint_t)u[5] << 16); pk.w = u[6] | ((uint_t)u[7] << 16);
        *(uint4*)(xT + (((size_t)b * 66 + yy) * 68 + xx) * 96 + cig * 8) = pk;
    }
}

// ---------------- Kernel 2b: implicit-GEMM 3x3 conv via MFMA bf16 -> seqT[b][l][c] bf16
__global__ __launch_bounds__(384, 2) void k_conv_mfma(const ushort_t* __restrict__ xT,
                                                      const ushort_t* __restrict__ Wbf,
                                                      ushort_t* __restrict__ seqT) {
    int tid = threadIdx.x;
    int w = tid >> 6, l = tid & 63;
    int n = l & 15, g = l >> 4;
    int blk = blockIdx.x;
    int b = blk >> 7, rem = blk & 127;
    int y = rem >> 1, half = rem & 1;
    int x0 = (half * 2 + (w & 1)) * 16;
    int co0 = (w >> 1) * 32;
    v4f acc0 = {0.f, 0.f, 0.f, 0.f};
    v4f acc1 = {0.f, 0.f, 0.f, 0.f};
    const ushort_t* xb = xT + (((size_t)b * 66 + y) * 68 + x0 + n) * 96 + g * 8;
    const ushort_t* aw = Wbf + ((size_t)co0 + n) * 96 + g * 8;
#pragma unroll
    for (int tap = 0; tap < 9; ++tap) {
        int dy = tap / 3, dx = tap % 3;
        const ushort_t* bp = xb + (dy * 68 + dx) * 96;
        const ushort_t* ap = aw + (size_t)tap * 96 * 96;
#pragma unroll
        for (int kk = 0; kk < 3; ++kk) {
            v8s bf = *(const v8s*)(bp + kk * 32);
            v8s a0 = *(const v8s*)(ap + kk * 32);
            v8s a1 = *(const v8s*)(ap + 16 * 96 + kk * 32);
            acc0 = __builtin_amdgcn_mfma_f32_16x16x32_bf16(a0, bf, acc0, 0, 0, 0);
            acc1 = __builtin_amdgcn_mfma_f32_16x16x32_bf16(a1, bf, acc1, 0, 0, 0);
        }
    }
    size_t sb = ((size_t)b * 4096 + y * 64 + x0 + n) * 96;
    ushort4 p0, p1;
    p0.x = f2bf(acc0[0]); p0.y = f2bf(acc0[1]); p0.z = f2bf(acc0[2]); p0.w = f2bf(acc0[3]);
    p1.x = f2bf(acc1[0]); p1.y = f2bf(acc1[1]); p1.z = f2bf(acc1[2]); p1.w = f2bf(acc1[3]);
    *(ushort4*)(seqT + sb + co0 + g * 4) = p0;
    *(ushort4*)(seqT + sb + co0 + 16 + g * 4) = p1;
}

// ---------------- Kernel 3: in_proj via MFMA -> xz[b][e][l] f32
__global__ __launch_bounds__(256, 3) void k_inproj(const ushort_t* __restrict__ seqT,
                                                   const ushort_t* __restrict__ Wibf,
                                                   float* __restrict__ xz) {
    int tid = threadIdx.x;
    int w = tid >> 6, l = tid & 63;
    int n = l & 15, g = l >> 4;
    int blk = blockIdx.x;
    int b = blk >> 8;
    int l0 = (blk & 255) * 16;
    int coh = w * 96;
    v4f acc[6];
#pragma unroll
    for (int mt = 0; mt < 6; ++mt) acc[mt] = (v4f){0.f, 0.f, 0.f, 0.f};
    const ushort_t* bp = seqT + ((size_t)b * 4096 + l0 + n) * 96 + g * 8;
    const ushort_t* ap = Wibf + ((size_t)coh + n) * 96 + g * 8;
#pragma unroll
    for (int kk = 0; kk < 3; ++kk) {
        v8s bf = *(const v8s*)(bp + kk * 32);
#pragma unroll
        for (int mt = 0; mt < 6; ++mt) {
            v8s af = *(const v8s*)(ap + mt * 16 * 96 + kk * 32);
            acc[mt] = __builtin_amdgcn_mfma_f32_16x16x32_bf16(af, bf, acc[mt], 0, 0, 0);
        }
    }
    float* ob = xz + (size_t)b * 384 * LL + l0 + n;
#pragma unroll
    for (int mt = 0; mt < 6; ++mt) {
        int e = coh + mt * 16 + g * 4;
#pragma unroll
        for (int r = 0; r < 4; ++r)
            ob[(size_t)(e + r) * LL] = acc[mt][r];
    }
}

// ---------------- Kernel 4: causal depthwise conv1d (k=4) + SiLU -> xc f32 + xcT bf16
__global__ __launch_bounds__(256) void k_conv1d(const float* __restrict__ xz,
                                                const float* __restrict__ w,
                                                const float* __restrict__ bias,
                                                float* __restrict__ xc,
                                                ushort_t* __restrict__ xcT) {
    int tid = blockIdx.x * 256 + threadIdx.x;   // B*192*1024 threads
    int tq = tid & 1023;
    int bd = tid >> 10;
    int d = bd % DIN, b = bd / DIN;
    const float* xin = xz + (size_t)(b * 384 + d) * LL;
    int t0 = tq * 4;
    float4 cur = *(const float4*)(xin + t0);
    float pm3 = 0.f, pm2 = 0.f, pm1 = 0.f;
    if (t0 > 0) {
        float4 prev = *(const float4*)(xin + t0 - 4);
        pm3 = prev.y; pm2 = prev.z; pm1 = prev.w;
    }
    float in[7] = {pm3, pm2, pm1, cur.x, cur.y, cur.z, cur.w};
    float w0 = w[d * 4 + 0], w1 = w[d * 4 + 1], w2 = w[d * 4 + 2], w3 = w[d * 4 + 3];
    float bb = bias[d];
    float o[4];
#pragma unroll
    for (int i = 0; i < 4; ++i) {
        float s = bb + w0 * in[i] + w1 * in[i + 1] + w2 * in[i + 2] + w3 * in[i + 3];
        o[i] = siluf(s);
    }
    float4 ov; ov.x = o[0]; ov.y = o[1]; ov.z = o[2]; ov.w = o[3];
    *(float4*)(xc + (size_t)(b * DIN + d) * LL + t0) = ov;
    ushort_t* xt = xcT + ((size_t)b * 4096 + t0) * DIN + d;
#pragma unroll
    for (int i = 0; i < 4; ++i)
        xt[(size_t)i * DIN] = f2bf(o[i]);
}

// ---------------- Kernel 5: x_proj via MFMA -> dtT [r][t]; BtP/CtP packed [t][16]
__global__ __launch_bounds__(256, 4) void k_xprojm(const ushort_t* __restrict__ xcT,
                                                   const ushort_t* __restrict__ Wxbf,
                                                   float* __restrict__ dtT,
                                                   float* __restrict__ BtP,
                                                   float* __restrict__ CtP) {
    int tid = threadIdx.x;
    int w = tid >> 6, l = tid & 63;
    int n = l & 15, g = l >> 4;
    int b = blockIdx.y;
    int l0 = blockIdx.x * 64 + w * 16;
    const ushort_t* bp = xcT + ((size_t)b * 4096 + l0 + n) * 192 + g * 8;
    const ushort_t* ap = Wxbf + (size_t)n * 192 + g * 8;
    v4f acc[3];
#pragma unroll
    for (int m = 0; m < 3; ++m) acc[m] = (v4f){0.f, 0.f, 0.f, 0.f};
#pragma unroll
    for (int kk = 0; kk < 6; ++kk) {
        v8s bf = *(const v8s*)(bp + kk * 32);
#pragma unroll
        for (int m = 0; m < 3; ++m) {
            v8s af = *(const v8s*)(ap + m * 16 * 192 + kk * 32);
            acc[m] = __builtin_amdgcn_mfma_f32_16x16x32_bf16(af, bf, acc[m], 0, 0, 0);
        }
    }
    float* dtb = dtT + (size_t)b * 6 * LL + l0 + n;
    float* Bb = BtP + ((size_t)b * LL + l0 + n) * 16;
    float* Cb = CtP + ((size_t)b * LL + l0 + n) * 16;
#pragma unroll
    for (int m = 0; m < 3; ++m)
#pragma unroll
        for (int r = 0; r < 4; ++r) {
            int e = m * 16 + g * 4 + r;
            float v = acc[m][r];
            if (e < 6)       dtb[(size_t)e * LL] = v;
            else if (e < 22) Bb[e - 6] = v;
            else if (e < 38) Cb[e - 22] = v;
        }
}

// ---------------- Kernel 6: dt_proj + softplus -> delta (B,192,L); reads dtT [r][t]
__global__ __launch_bounds__(256) void k_dtproj(const float* __restrict__ dtT,
                                                const float* __restrict__ dtw,
                                                const float* __restrict__ dtb,
                                                float* __restrict__ delta) {
    int tx = threadIdx.x, ty = threadIdx.y;   // (64,4)
    int b = blockIdx.y;
    int l = blockIdx.x * 64 + tx;
    int d0 = blockIdx.z * 48 + ty * 12;
    const float* dbase = dtT + (size_t)b * 6 * LL + l;
    float r0 = dbase[0], r1 = dbase[LL], r2 = dbase[2 * LL];
    float r3 = dbase[3 * LL], r4 = dbase[4 * LL], r5 = dbase[5 * LL];
#pragma unroll
    for (int j = 0; j < 12; ++j) {
        int dd = d0 + j;
        const float* wr2 = dtw + dd * 6;
        float s = dtb[dd] + wr2[0] * r0 + wr2[1] * r1 + wr2[2] * r2
                          + wr2[3] * r3 + wr2[4] * r4 + wr2[5] * r5;
        float e = fexp2(s * 1.44269504f);
        float sp = 0.69314718f * flog2(1.f + e);
        delta[((size_t)b * DIN + dd) * LL + l] = sp;
    }
}

// ---------------- Kernel 7: chunked selective scan + gate -> ygT bf16 (aliased on xz)
// B/C packed per-t: lane-group n=0..15 reads one 64B line per t.
__global__ __launch_bounds__(512, 6) void k_scan(const float* __restrict__ delta,
                                                 const float* __restrict__ xc,
                                                 const float* __restrict__ BtP,
                                                 const float* __restrict__ CtP,
                                                 const float* __restrict__ A_log,
                                                 const float* __restrict__ Dp,
                                                 float* __restrict__ xz) {
    __shared__ float s_d[32 * 132];       // chunk c at c*132 (+4 pad)
    __shared__ float s_u[32 * 132];
    __shared__ float s_a[32][17];
    __shared__ float s_h[32][17];
    int tid = threadIdx.x;
    int n = tid & 15, cg = tid >> 4;      // 32 chunks x 16 states
    int bd = blockIdx.x;
    int d = bd % DIN, b = bd / DIN;
    const float* drow = delta + (size_t)(b * DIN + d) * LL;
    const float* urow = xc    + (size_t)(b * DIN + d) * LL;
    const float* zrow = xz    + (size_t)(b * 384 + DIN + d) * LL;
    ushort_t* ygb     = (ushort_t*)(xz + (size_t)b * 384 * LL);
    float A2 = -__expf(A_log[d * NST + n]) * 1.44269504f;   // for fexp2
    float Dd = Dp[d];

    {
        int t8 = tid * 8;
        int li = ((t8 >> 7) * 132) + (t8 & 127);
        *(float4*)&s_d[li]     = *(const float4*)(drow + t8);
        *(float4*)&s_d[li + 4] = *(const float4*)(drow + t8 + 4);
        *(float4*)&s_u[li]     = *(const float4*)(urow + t8);
        *(float4*)&s_u[li + 4] = *(const float4*)(urow + t8 + 4);
    }
    __syncthreads();

    int t0 = cg * 128;
    int lb = cg * 132;
    const float* pB = BtP + ((size_t)b * LL + t0) * 16 + n;
    const float* pC = CtP + ((size_t)b * LL + t0) * 16 + n;

    // ---- phase 1: per-chunk aggregates; aP in log space (sum du, one exp)
    float h = 0.f, sdu = 0.f;
    float4 du_c = *(float4*)&s_d[lb];
    float4 u_c  = *(float4*)&s_u[lb];
    float B0 = pB[0], B1 = pB[16], B2 = pB[32], B3 = pB[48];
    for (int s = 0; s < 31; ++s) {
        int ln = lb + s * 4 + 4;
        const float* pBn = pB + s * 64 + 64;
        float4 du_n = *(float4*)&s_d[ln];
        float4 u_n  = *(float4*)&s_u[ln];
        float Bn0 = pBn[0], Bn1 = pBn[16], Bn2 = pBn[32], Bn3 = pBn[48];
        float a0 = fexp2(du_c.x * A2), a1 = fexp2(du_c.y * A2);
        float a2 = fexp2(du_c.z * A2), a3 = fexp2(du_c.w * A2);
        h = fmaf(a0, h, (du_c.x * u_c.x) * B0);
        h = fmaf(a1, h, (du_c.y * u_c.y) * B1);
        h = fmaf(a2, h, (du_c.z * u_c.z) * B2);
        h = fmaf(a3, h, (du_c.w * u_c.w) * B3);
        sdu += (du_c.x + du_c.y) + (du_c.z + du_c.w);
        du_c = du_n; u_c = u_n; B0 = Bn0; B1 = Bn1; B2 = Bn2; B3 = Bn3;
    }
    {
        float a0 = fexp2(du_c.x * A2), a1 = fexp2(du_c.y * A2);
        float a2 = fexp2(du_c.z * A2), a3 = fexp2(du_c.w * A2);
        h = fmaf(a0, h, (du_c.x * u_c.x) * B0);
        h = fmaf(a1, h, (du_c.y * u_c.y) * B1);
        h = fmaf(a2, h, (du_c.z * u_c.z) * B2);
        h = fmaf(a3, h, (du_c.w * u_c.w) * B3);
        sdu += (du_c.x + du_c.y) + (du_c.z + du_c.w);
    }
    s_a[cg][n] = fexp2(sdu * A2);
    s_h[cg][n] = h;
    __syncthreads();

    // ---- phase 2: Kogge-Stone scan of 32 chunk aggregates (per n)
    {
        int l = tid & 63, w = tid >> 6;
        int c = l & 31, nn = (w << 1) | (l >> 5);
        float a  = s_a[c][nn];
        float hh = s_h[c][nn];
#pragma unroll
        for (int st = 1; st < 32; st <<= 1) {
            float ap = __shfl_up(a, st, 32);
            float hp = __shfl_up(hh, st, 32);
            bool ok = (c >= st);
            hh = ok ? fmaf(a, hp, hh) : hh;
            a  = ok ? a * ap : a;
        }
        float h0 = __shfl_up(hh, 1, 32);
        if (c == 0) h0 = 0.f;
        s_a[c][nn] = h0;
    }
    __syncthreads();

    // ---- phase 3: recompute with h0; reduce over n; lane-t epilogue; store
    h = s_a[cg][n];
    const int j = n & 3;
    const bool e1 = (j == 1), e2 = (j == 2), e3 = (j == 3);
    du_c = *(float4*)&s_d[lb];
    u_c  = *(float4*)&s_u[lb];
    B0 = pB[0]; B1 = pB[16]; B2 = pB[32]; B3 = pB[48];
    float C0 = pC[0], C1 = pC[16], C2 = pC[32], C3 = pC[48];
    float4 z_c = *(const float4*)(zrow + t0);
    for (int s = 0; s < 32; ++s) {
        float4 du_n, u_n, z_n;
        float Bn0, Bn1, Bn2, Bn3, Cn0, Cn1, Cn2, Cn3;
        if (s < 31) {
            int ln = lb + s * 4 + 4;
            const float* pBn = pB + s * 64 + 64;
            const float* pCn = pC + s * 64 + 64;
            du_n = *(float4*)&s_d[ln];
            u_n  = *(float4*)&s_u[ln];
            Bn0 = pBn[0]; Bn1 = pBn[16]; Bn2 = pBn[32]; Bn3 = pBn[48];
            Cn0 = pCn[0]; Cn1 = pCn[16]; Cn2 = pCn[32]; Cn3 = pCn[48];
            z_n = *(const float4*)(zrow + t0 + s * 4 + 4);
        }
        float a0 = fexp2(du_c.x * A2), a1 = fexp2(du_c.y * A2);
        float a2 = fexp2(du_c.z * A2), a3 = fexp2(du_c.w * A2);
        h = fmaf(a0, h, (du_c.x * u_c.x) * B0); float p0 = h * C0;
        h = fmaf(a1, h, (du_c.y * u_c.y) * B1); float p1 = h * C1;
        h = fmaf(a2, h, (du_c.z * u_c.z) * B2); float p2 = h * C2;
        h = fmaf(a3, h, (du_c.w * u_c.w) * B3); float p3 = h * C3;
        p0 = rsum16(p0); p1 = rsum16(p1); p2 = rsum16(p2); p3 = rsum16(p3);
        // lane-t specialization: lane handles t-offset j = n&3 (uniform p/u/z per group)
        float pj = e3 ? p3 : (e2 ? p2 : (e1 ? p1 : p0));
        float uj = e3 ? u_c.w : (e2 ? u_c.z : (e1 ? u_c.y : u_c.x));
        float zj = e3 ? z_c.w : (e2 ? z_c.z : (e1 ? z_c.y : z_c.x));
        float yj = fmaf(Dd, uj, pj) * siluf(zj);
        if (n < 4)
            ygb[(size_t)(t0 + s * 4 + n) * DIN + d] = f2bf(yj);
        du_c = du_n; u_c = u_n; z_c = z_n;
        B0 = Bn0; B1 = Bn1; B2 = Bn2; B3 = Bn3;
        C0 = Cn0; C1 = Cn1; C2 = Cn2; C3 = Cn3;
    }
}

// ---------------- Kernel 8: out_proj via MFMA: out[b][c][l] f32 = W[c][d] * ygT[l][d]
__global__ __launch_bounds__(512, 2) void k_outproj(const float* __restrict__ xzBase,
                                                    const ushort_t* __restrict__ Wobf,
                                                    float* __restrict__ out) {
    int tid = threadIdx.x;
    int w = tid >> 6, l = tid & 63;
    int n = l & 15, g = l >> 4;
    int b = blockIdx.y;
    int l0 = blockIdx.x * 64 + (w >> 1) * 16;
    int c0 = (w & 1) * 48;
    const ushort_t* ygb = (const ushort_t*)(xzBase + (size_t)b * 384 * LL);
    const ushort_t* bp = ygb + ((size_t)l0 + n) * 192 + g * 8;
    const ushort_t* ap = Wobf + ((size_t)c0 + n) * 192 + g * 8;
    v4f acc[3];
#pragma unroll
    for (int m = 0; m < 3; ++m) acc[m] = (v4f){0.f, 0.f, 0.f, 0.f};
#pragma unroll
    for (int kk = 0; kk < 6; ++kk) {
        v8s bf = *(const v8s*)(bp + kk * 32);
#pragma unroll
        for (int m = 0; m < 3; ++m) {
            v8s af = *(const v8s*)(ap + m * 16 * 192 + kk * 32);
            acc[m] = __builtin_amdgcn_mfma_f32_16x16x32_bf16(af, bf, acc[m], 0, 0, 0);
        }
    }
    float* ob = out + (size_t)b * 96 * LL + l0 + n;
#pragma unroll
    for (int m = 0; m < 3; ++m)
#pragma unroll
        for (int r = 0; r < 4; ++r)
            ob[(size_t)(c0 + m * 16 + g * 4 + r) * LL] = acc[m][r];
}

extern "C" void kernel_launch(void* const* d_in, const int* in_sizes, int n_in,
                              void* d_out, int out_size, void* d_ws, size_t ws_size,
                              hipStream_t stream) {
    const float* x         = (const float*)d_in[0];
    const float* proj_w    = (const float*)d_in[1];
    const float* dconv_w   = (const float*)d_in[2];
    const float* in_proj_w = (const float*)d_in[3];
    const float* conv1d_w  = (const float*)d_in[4];
    const float* conv1d_b  = (const float*)d_in[5];
    const float* x_proj_w  = (const float*)d_in[6];
    const float* dt_proj_w = (const float*)d_in[7];
    const float* dt_proj_b = (const float*)d_in[8];
    const float* A_log     = (const float*)d_in[9];
    const float* Dp        = (const float*)d_in[10];
    const float* out_proj_w= (const float*)d_in[11];
    float* out = (float*)d_out;
    float* ws  = (float*)d_ws;

    // carve (float units)
    ushort_t* Wbf  = (ushort_t*)ws;                      // 82,944 sh -> 41,472 fl
    ushort_t* Wibf = (ushort_t*)(ws + 41472);            // 36,864 sh -> 18,432 fl
    ushort_t* Wobf = (ushort_t*)(ws + 59904);            // 18,432 sh ->  9,216 fl
    ushort_t* Wxbf = (ushort_t*)(ws + 69120);            //  9,216 sh ->  4,608 fl
    ushort_t* xT   = (ushort_t*)(ws + 73728);            // 1,723,392 sh -> 861,696 fl
    ushort_t* seqT = (ushort_t*)(ws + 935424);           // 1,572,864 sh -> 786,432 fl
    float* xz   = ws + 1721856;                          // 4*384*4096 = 6,291,456
    float* xc   = xz + 6291456;                          // 3,145,728
    float* dtT  = xc + 3145728;                          // 4*6*4096   =    98,304
    float* BtP  = dtT + 98304;                           // 4*4096*16  =   262,144
    float* CtP  = BtP + 262144;                          // 4*4096*16  =   262,144
    float* delta= CtP + 262144;                          // 3,145,728
    ushort_t* xcT = (ushort_t*)delta;                    // alias: dead once delta written
    // ygT aliases xz lower half per-batch (xin dead after conv1d)

    k_merge_w<<<dim3(324), dim3(256), 0, stream>>>(proj_w, dconv_w, Wbf);
    k_cvt_all<<<dim3(252), dim3(256), 0, stream>>>(in_proj_w, out_proj_w, x_proj_w,
                                                   Wibf, Wobf, Wxbf);
    k_xpad<<<dim3(66, 4), dim3(256), 0, stream>>>(x, xT);
    k_conv_mfma<<<dim3(512), dim3(384), 0, stream>>>(xT, Wbf, seqT);
    k_inproj<<<dim3(1024), dim3(256), 0, stream>>>(seqT, Wibf, xz);
    k_conv1d<<<dim3(3072), dim3(256), 0, stream>>>(xz, conv1d_w, conv1d_b, xc, xcT);
    k_xprojm<<<dim3(64, 4), dim3(256), 0, stream>>>(xcT, Wxbf, dtT, BtP, CtP);
    k_dtproj<<<dim3(64, 4, 4), dim3(64, 4), 0, stream>>>(dtT, dt_proj_w, dt_proj_b, delta);
    k_scan<<<dim3(768), dim3(512), 0, stream>>>(delta, xc, BtP, CtP, A_log, Dp, xz);
    k_outproj<<<dim3(64, 4), dim3(512), 0, stream>>>(xz, Wobf, out);
}

// Round 9
// 129.652 us; speedup vs baseline: 1.7379x; 1.1695x over previous
//
#include <hip/hip_runtime.h>
#include <math.h>

#define LL    4096
#define CDIM  96
#define DIN   192
#define NST   16
#define XE    38   // dt_rank(6) + 2*16

typedef __attribute__((ext_vector_type(8))) short v8s;
typedef __attribute__((ext_vector_type(4))) float v4f;
typedef unsigned short ushort_t;
typedef unsigned int uint_t;

#if __has_builtin(__builtin_amdgcn_exp2f)
__device__ __forceinline__ float fexp2(float x) { return __builtin_amdgcn_exp2f(x); }
#else
__device__ __forceinline__ float fexp2(float x) { return exp2f(x); }
#endif
#if __has_builtin(__builtin_amdgcn_logf)
__device__ __forceinline__ float flog2(float x) { return __builtin_amdgcn_logf(x); }
#else
__device__ __forceinline__ float flog2(float x) { return __log2f(x); }
#endif

__device__ __forceinline__ float siluf(float x) {
    return x * __builtin_amdgcn_rcpf(1.f + fexp2(-1.44269504f * x));
}
__device__ __forceinline__ ushort_t f2bf(float f) {
    uint_t u = __builtin_bit_cast(uint_t, f);
    return (ushort_t)((u + 0x7fffu + ((u >> 16) & 1u)) >> 16);
}

// ---------------- Kernel 1: all weight prep in ONE launch
// idx<82944: merge proj(1x1) into dconv(3x3) -> Wbf[tap][co][ci] bf16; then cvt in/out/x_proj
__global__ __launch_bounds__(256) void k_prep(const float* __restrict__ proj_w,
                                              const float* __restrict__ dconv_w,
                                              const float* __restrict__ in_proj_w,
                                              const float* __restrict__ out_proj_w,
                                              const float* __restrict__ x_proj_w,
                                              ushort_t* __restrict__ Wbf,
                                              ushort_t* __restrict__ Wibf,
                                              ushort_t* __restrict__ Wobf,
                                              ushort_t* __restrict__ Wxbf) {
    int i = blockIdx.x * 256 + threadIdx.x;
    if (i < 82944) {
        int k = i % 9;
        int c = (i / 9) % 96;
        int o = i / 864;
        float s = 0.f;
        for (int j = 0; j < 192; ++j)
            s += dconv_w[(o * 192 + j) * 9 + k] * proj_w[j * 96 + c];
        Wbf[(k * 96 + o) * 96 + c] = f2bf(s);
        return;
    }
    i -= 82944;
    if (i < 36864) { Wibf[i] = f2bf(in_proj_w[i]); return; }
    i -= 36864;
    if (i < 18432) { Wobf[i] = f2bf(out_proj_w[i]); return; }
    i -= 18432;
    if (i < 9216) {
        int e = i / 192;
        Wxbf[i] = (e < XE) ? f2bf(x_proj_w[i]) : (ushort_t)0;
    }
}

// ---------------- Kernel 2a: x (B,96,64,64) f32 -> xT[b][66][68][96] bf16, zero halo
__global__ __launch_bounds__(256) void k_xpad(const float* __restrict__ x,
                                              ushort_t* __restrict__ xT) {
    int yy = blockIdx.x;        // 0..65
    int b  = blockIdx.y;
    int yv = yy - 1;
    for (int i = threadIdx.x; i < 68 * 12; i += 256) {
        int xx = i % 68, cig = i / 68;
        int xv = xx - 1;
        ushort_t u[8];
        if (yv >= 0 && yv < 64 && xv >= 0 && xv < 64) {
            const float* sp = x + ((size_t)(b * 96 + cig * 8)) * LL + yv * 64 + xv;
#pragma unroll
            for (int j = 0; j < 8; ++j) u[j] = f2bf(sp[j * LL]);
        } else {
#pragma unroll
            for (int j = 0; j < 8; ++j) u[j] = 0;
        }
        uint4 pk;
        pk.x = u[0] | ((uint_t)u[1] << 16); pk.y = u[2] | ((uint_t)u[3] << 16);
        pk.z = u[4] | ((uint_t)u[5] << 16); pk.w = u[6] | ((uint_t)u[7] << 16);
        *(uint4*)(xT + (((size_t)b * 66 + yy) * 68 + xx) * 96 + cig * 8) = pk;
    }
}

// ---------------- Kernel 2b: FUSED 3x3-conv + in_proj via MFMA -> xz[b][e][l] f32
// block (b, y, half) covers 32 l; conv result staged in LDS (stride 104), then K=96 GEMM.
__global__ __launch_bounds__(384, 2) void k_convin(const ushort_t* __restrict__ xT,
                                                   const ushort_t* __restrict__ Wbf,
                                                   const ushort_t* __restrict__ Wibf,
                                                   float* __restrict__ xz) {
    __shared__ ushort_t s_seq[32 * 104];
    int tid = threadIdx.x;
    int w = tid >> 6, l = tid & 63;
    int n = l & 15, g = l >> 4;
    int blk = blockIdx.x;
    int b = blk >> 7, rem = blk & 127;
    int y = rem >> 1, half = rem & 1;
    int lx = (w & 1) * 16;              // local x-tile base
    int x0 = half * 32 + lx;            // x within the 64-wide row
    int co0 = (w >> 1) * 32;
    // ---- conv 3x3 (9 taps x K=96)
    v4f acc0 = {0.f, 0.f, 0.f, 0.f};
    v4f acc1 = {0.f, 0.f, 0.f, 0.f};
    const ushort_t* xb = xT + (((size_t)b * 66 + y) * 68 + x0 + n) * 96 + g * 8;
    const ushort_t* aw = Wbf + ((size_t)co0 + n) * 96 + g * 8;
#pragma unroll
    for (int tap = 0; tap < 9; ++tap) {
        int dy = tap / 3, dx = tap % 3;
        const ushort_t* bp = xb + (dy * 68 + dx) * 96;
        const ushort_t* ap = aw + (size_t)tap * 9216;
#pragma unroll
        for (int kk = 0; kk < 3; ++kk) {
            v8s bf = *(const v8s*)(bp + kk * 32);
            v8s a0 = *(const v8s*)(ap + kk * 32);
            v8s a1 = *(const v8s*)(ap + 1536 + kk * 32);
            acc0 = __builtin_amdgcn_mfma_f32_16x16x32_bf16(a0, bf, acc0, 0, 0, 0);
            acc1 = __builtin_amdgcn_mfma_f32_16x16x32_bf16(a1, bf, acc1, 0, 0, 0);
        }
    }
    // ---- stage conv output in LDS: [32 local l][104 pad] bf16
    {
        int ll = lx + n;
        ushort_t* sp = s_seq + ll * 104 + co0 + g * 4;
        ushort4 p0, p1;
        p0.x = f2bf(acc0[0]); p0.y = f2bf(acc0[1]); p0.z = f2bf(acc0[2]); p0.w = f2bf(acc0[3]);
        p1.x = f2bf(acc1[0]); p1.y = f2bf(acc1[1]); p1.z = f2bf(acc1[2]); p1.w = f2bf(acc1[3]);
        *(ushort4*)sp = p0;
        *(ushort4*)(sp + 16) = p1;
    }
    __syncthreads();
    // ---- in_proj: wave w handles e in [w*64, w*64+64)
    int coh = w * 64;
    v4f acc[4][2];
#pragma unroll
    for (int mt = 0; mt < 4; ++mt)
#pragma unroll
        for (int lt = 0; lt < 2; ++lt) acc[mt][lt] = (v4f){0.f, 0.f, 0.f, 0.f};
    const ushort_t* ap2 = Wibf + ((size_t)coh + n) * 96 + g * 8;
#pragma unroll
    for (int lt = 0; lt < 2; ++lt) {
        const ushort_t* bp2 = s_seq + (lt * 16 + n) * 104 + g * 8;
#pragma unroll
        for (int kk = 0; kk < 3; ++kk) {
            v8s bf = *(const v8s*)(bp2 + kk * 32);
#pragma unroll
            for (int mt = 0; mt < 4; ++mt) {
                v8s af = *(const v8s*)(ap2 + mt * 16 * 96 + kk * 32);
                acc[mt][lt] = __builtin_amdgcn_mfma_f32_16x16x32_bf16(af, bf, acc[mt][lt], 0, 0, 0);
            }
        }
    }
    int l0g = y * 64 + half * 32;
    float* ob = xz + (size_t)b * 384 * LL + l0g + n;
#pragma unroll
    for (int mt = 0; mt < 4; ++mt) {
        int e = coh + mt * 16 + g * 4;
#pragma unroll
        for (int lt = 0; lt < 2; ++lt)
#pragma unroll
            for (int r = 0; r < 4; ++r)
                ob[(size_t)(e + r) * LL + lt * 16] = acc[mt][lt][r];
    }
}

// ---------------- Kernel 4: causal depthwise conv1d (k=4) + SiLU -> xc f32 + xcT bf16
// block = 64 d x 16 t (256 thr: d_l = tid>>2, tg = tid&3) -> xcT stores 32B-grouped
__global__ __launch_bounds__(256) void k_conv1d(const float* __restrict__ xz,
                                                const float* __restrict__ w,
                                                const float* __restrict__ bias,
                                                float* __restrict__ xc,
                                                ushort_t* __restrict__ xcT) {
    int tid = threadIdx.x;
    int d_l = tid >> 2, tg = tid & 3;
    int b = blockIdx.z, dg = blockIdx.y, tt = blockIdx.x;
    int d = dg * 64 + d_l;
    int t0 = tt * 16 + tg * 4;
    const float* xin = xz + (size_t)(b * 384 + d) * LL;
    float4 cur = *(const float4*)(xin + t0);
    float pm3 = 0.f, pm2 = 0.f, pm1 = 0.f;
    if (t0 > 0) {
        float4 prev = *(const float4*)(xin + t0 - 4);
        pm3 = prev.y; pm2 = prev.z; pm1 = prev.w;
    }
    float in[7] = {pm3, pm2, pm1, cur.x, cur.y, cur.z, cur.w};
    float w0 = w[d * 4 + 0], w1 = w[d * 4 + 1], w2 = w[d * 4 + 2], w3 = w[d * 4 + 3];
    float bb = bias[d];
    float o[4];
#pragma unroll
    for (int i = 0; i < 4; ++i) {
        float s = bb + w0 * in[i] + w1 * in[i + 1] + w2 * in[i + 2] + w3 * in[i + 3];
        o[i] = siluf(s);
    }
    float4 ov; ov.x = o[0]; ov.y = o[1]; ov.z = o[2]; ov.w = o[3];
    *(float4*)(xc + (size_t)(b * DIN + d) * LL + t0) = ov;
    ushort_t* xt = xcT + ((size_t)b * 4096 + t0) * DIN + d;
#pragma unroll
    for (int i = 0; i < 4; ++i)
        xt[(size_t)i * DIN] = f2bf(o[i]);
}

// ---------------- Kernel 5: x_proj via MFMA -> dtT [r][t]; BtP/CtP packed [t][16]
__global__ __launch_bounds__(256, 4) void k_xprojm(const ushort_t* __restrict__ xcT,
                                                   const ushort_t* __restrict__ Wxbf,
                                                   float* __restrict__ dtT,
                                                   float* __restrict__ BtP,
                                                   float* __restrict__ CtP) {
    int tid = threadIdx.x;
    int w = tid >> 6, l = tid & 63;
    int n = l & 15, g = l >> 4;
    int b = blockIdx.y;
    int l0 = blockIdx.x * 64 + w * 16;
    const ushort_t* bp = xcT + ((size_t)b * 4096 + l0 + n) * 192 + g * 8;
    const ushort_t* ap = Wxbf + (size_t)n * 192 + g * 8;
    v4f acc[3];
#pragma unroll
    for (int m = 0; m < 3; ++m) acc[m] = (v4f){0.f, 0.f, 0.f, 0.f};
#pragma unroll
    for (int kk = 0; kk < 6; ++kk) {
        v8s bf = *(const v8s*)(bp + kk * 32);
#pragma unroll
        for (int m = 0; m < 3; ++m) {
            v8s af = *(const v8s*)(ap + m * 16 * 192 + kk * 32);
            acc[m] = __builtin_amdgcn_mfma_f32_16x16x32_bf16(af, bf, acc[m], 0, 0, 0);
        }
    }
    float* dtb = dtT + (size_t)b * 6 * LL + l0 + n;
    float* Bb = BtP + ((size_t)b * LL + l0 + n) * 16;
    float* Cb = CtP + ((size_t)b * LL + l0 + n) * 16;
#pragma unroll
    for (int m = 0; m < 3; ++m)
#pragma unroll
        for (int r = 0; r < 4; ++r) {
            int e = m * 16 + g * 4 + r;
            float v = acc[m][r];
            if (e < 6)       dtb[(size_t)e * LL] = v;
            else if (e < 22) Bb[e - 6] = v;
            else if (e < 38) Cb[e - 22] = v;
        }
}

// ---------------- Kernel 6: dt_proj + softplus -> delta (B,192,L); reads dtT [r][t]
__global__ __launch_bounds__(256) void k_dtproj(const float* __restrict__ dtT,
                                                const float* __restrict__ dtw,
                                                const float* __restrict__ dtb,
                                                float* __restrict__ delta) {
    int tx = threadIdx.x, ty = threadIdx.y;   // (64,4)
    int b = blockIdx.y;
    int l = blockIdx.x * 64 + tx;
    int d0 = blockIdx.z * 48 + ty * 12;
    const float* dbase = dtT + (size_t)b * 6 * LL + l;
    float r0 = dbase[0], r1 = dbase[LL], r2 = dbase[2 * LL];
    float r3 = dbase[3 * LL], r4 = dbase[4 * LL], r5 = dbase[5 * LL];
#pragma unroll
    for (int j = 0; j < 12; ++j) {
        int dd = d0 + j;
        const float* wr2 = dtw + dd * 6;
        float s = dtb[dd] + wr2[0] * r0 + wr2[1] * r1 + wr2[2] * r2
                          + wr2[3] * r3 + wr2[4] * r4 + wr2[5] * r5;
        float e = fexp2(s * 1.44269504f);
        float sp = 0.69314718f * flog2(1.f + e);
        delta[((size_t)b * DIN + dd) * LL + l] = sp;
    }
}

// ---------------- Kernel 7: chunked selective scan + gate -> ygT bf16 (aliased on xz)
__global__ __launch_bounds__(512, 6) void k_scan(const float* __restrict__ delta,
                                                 const float* __restrict__ xc,
                                                 const float* __restrict__ BtP,
                                                 const float* __restrict__ CtP,
                                                 const float* __restrict__ A_log,
                                                 const float* __restrict__ Dp,
                                                 float* __restrict__ xz) {
    __shared__ float s_d[32 * 132];       // chunk c at c*132 (+4 pad)
    __shared__ float s_u[32 * 132];
    __shared__ float s_a[32][17];
    __shared__ float s_h[32][17];
    int tid = threadIdx.x;
    int n = tid & 15, cg = tid >> 4;      // 32 chunks x 16 states
    int bd = blockIdx.x;
    int d = bd % DIN, b = bd / DIN;
    const float* drow = delta + (size_t)(b * DIN + d) * LL;
    const float* urow = xc    + (size_t)(b * DIN + d) * LL;
    const float* zrow = xz    + (size_t)(b * 384 + DIN + d) * LL;
    ushort_t* ygb     = (ushort_t*)(xz + (size_t)b * 384 * LL);
    float A2 = -__expf(A_log[d * NST + n]) * 1.44269504f;   // for fexp2
    float Dd = Dp[d];

    {
        int t8 = tid * 8;
        int li = ((t8 >> 7) * 132) + (t8 & 127);
        *(float4*)&s_d[li]     = *(const float4*)(drow + t8);
        *(float4*)&s_d[li + 4] = *(const float4*)(drow + t8 + 4);
        *(float4*)&s_u[li]     = *(const float4*)(urow + t8);
        *(float4*)&s_u[li + 4] = *(const float4*)(urow + t8 + 4);
    }
    __syncthreads();

    int t0 = cg * 128;
    int lb = cg * 132;
    const float* pB = BtP + ((size_t)b * LL + t0) * 16 + n;
    const float* pC = CtP + ((size_t)b * LL + t0) * 16 + n;

    // ---- phase 1: per-chunk aggregates; aP in log space (sum du, one exp)
    float h = 0.f, sdu = 0.f;
    float4 du_c = *(float4*)&s_d[lb];
    float4 u_c  = *(float4*)&s_u[lb];
    float B0 = pB[0], B1 = pB[16], B2 = pB[32], B3 = pB[48];
    for (int s = 0; s < 31; ++s) {
        int ln = lb + s * 4 + 4;
        const float* pBn = pB + s * 64 + 64;
        float4 du_n = *(float4*)&s_d[ln];
        float4 u_n  = *(float4*)&s_u[ln];
        float Bn0 = pBn[0], Bn1 = pBn[16], Bn2 = pBn[32], Bn3 = pBn[48];
        float a0 = fexp2(du_c.x * A2), a1 = fexp2(du_c.y * A2);
        float a2 = fexp2(du_c.z * A2), a3 = fexp2(du_c.w * A2);
        h = fmaf(a0, h, (du_c.x * u_c.x) * B0);
        h = fmaf(a1, h, (du_c.y * u_c.y) * B1);
        h = fmaf(a2, h, (du_c.z * u_c.z) * B2);
        h = fmaf(a3, h, (du_c.w * u_c.w) * B3);
        sdu += (du_c.x + du_c.y) + (du_c.z + du_c.w);
        du_c = du_n; u_c = u_n; B0 = Bn0; B1 = Bn1; B2 = Bn2; B3 = Bn3;
    }
    {
        float a0 = fexp2(du_c.x * A2), a1 = fexp2(du_c.y * A2);
        float a2 = fexp2(du_c.z * A2), a3 = fexp2(du_c.w * A2);
        h = fmaf(a0, h, (du_c.x * u_c.x) * B0);
        h = fmaf(a1, h, (du_c.y * u_c.y) * B1);
        h = fmaf(a2, h, (du_c.z * u_c.z) * B2);
        h = fmaf(a3, h, (du_c.w * u_c.w) * B3);
        sdu += (du_c.x + du_c.y) + (du_c.z + du_c.w);
    }
    s_a[cg][n] = fexp2(sdu * A2);
    s_h[cg][n] = h;
    __syncthreads();

    // ---- phase 2: Kogge-Stone scan of 32 chunk aggregates (per n)
    {
        int l = tid & 63, w = tid >> 6;
        int c = l & 31, nn = (w << 1) | (l >> 5);
        float a  = s_a[c][nn];
        float hh = s_h[c][nn];
#pragma unroll
        for (int st = 1; st < 32; st <<= 1) {
            float ap = __shfl_up(a, st, 32);
            float hp = __shfl_up(hh, st, 32);
            bool ok = (c >= st);
            hh = ok ? fmaf(a, hp, hh) : hh;
            a  = ok ? a * ap : a;
        }
        float h0 = __shfl_up(hh, 1, 32);
        if (c == 0) h0 = 0.f;
        s_a[c][nn] = h0;
    }
    __syncthreads();

    // ---- phase 3: recompute with h0; partial-butterfly reduce; lane-t epilogue
    h = s_a[cg][n];
    const int j = n & 3;
    const bool e1 = (j == 1), e2 = (j == 2), e3 = (j == 3);
    du_c = *(float4*)&s_d[lb];
    u_c  = *(float4*)&s_u[lb];
    B0 = pB[0]; B1 = pB[16]; B2 = pB[32]; B3 = pB[48];
    float C0 = pC[0], C1 = pC[16], C2 = pC[32], C3 = pC[48];
    float4 z_c = *(const float4*)(zrow + t0);
    for (int s = 0; s < 32; ++s) {
        float4 du_n, u_n, z_n;
        float Bn0, Bn1, Bn2, Bn3, Cn0, Cn1, Cn2, Cn3;
        if (s < 31) {
            int ln = lb + s * 4 + 4;
            const float* pBn = pB + s * 64 + 64;
            const float* pCn = pC + s * 64 + 64;
            du_n = *(float4*)&s_d[ln];
            u_n  = *(float4*)&s_u[ln];
            Bn0 = pBn[0]; Bn1 = pBn[16]; Bn2 = pBn[32]; Bn3 = pBn[48];
            Cn0 = pCn[0]; Cn1 = pCn[16]; Cn2 = pCn[32]; Cn3 = pCn[48];
            z_n = *(const float4*)(zrow + t0 + s * 4 + 4);
        }
        float a0 = fexp2(du_c.x * A2), a1 = fexp2(du_c.y * A2);
        float a2 = fexp2(du_c.z * A2), a3 = fexp2(du_c.w * A2);
        h = fmaf(a0, h, (du_c.x * u_c.x) * B0); float p0 = h * C0;
        h = fmaf(a1, h, (du_c.y * u_c.y) * B1); float p1 = h * C1;
        h = fmaf(a2, h, (du_c.z * u_c.z) * B2); float p2 = h * C2;
        h = fmaf(a3, h, (du_c.w * u_c.w) * B3); float p3 = h * C3;
        // partial butterfly: quad sums for all 4 p's (xor 1,2)
        p0 += __shfl_xor(p0, 1); p0 += __shfl_xor(p0, 2);
        p1 += __shfl_xor(p1, 1); p1 += __shfl_xor(p1, 2);
        p2 += __shfl_xor(p2, 1); p2 += __shfl_xor(p2, 2);
        p3 += __shfl_xor(p3, 1); p3 += __shfl_xor(p3, 2);
        // each lane keeps only its t-offset j = n&3, finish across quads (xor 4,8)
        float pj = e3 ? p3 : (e2 ? p2 : (e1 ? p1 : p0));
        pj += __shfl_xor(pj, 4); pj += __shfl_xor(pj, 8);
        float uj = e3 ? u_c.w : (e2 ? u_c.z : (e1 ? u_c.y : u_c.x));
        float zj = e3 ? z_c.w : (e2 ? z_c.z : (e1 ? z_c.y : z_c.x));
        float yj = fmaf(Dd, uj, pj) * siluf(zj);
        if (n < 4)
            ygb[(size_t)(t0 + s * 4 + n) * DIN + d] = f2bf(yj);
        du_c = du_n; u_c = u_n; z_c = z_n;
        B0 = Bn0; B1 = Bn1; B2 = Bn2; B3 = Bn3;
        C0 = Cn0; C1 = Cn1; C2 = Cn2; C3 = Cn3;
    }
}

// ---------------- Kernel 8: out_proj via MFMA: out[b][c][l] f32 = W[c][d] * ygT[l][d]
__global__ __launch_bounds__(512, 2) void k_outproj(const float* __restrict__ xzBase,
                                                    const ushort_t* __restrict__ Wobf,
                                                    float* __restrict__ out) {
    int tid = threadIdx.x;
    int w = tid >> 6, l = tid & 63;
    int n = l & 15, g = l >> 4;
    int b = blockIdx.y;
    int l0 = blockIdx.x * 64 + (w >> 1) * 16;
    int c0 = (w & 1) * 48;
    const ushort_t* ygb = (const ushort_t*)(xzBase + (size_t)b * 384 * LL);
    const ushort_t* bp = ygb + ((size_t)l0 + n) * 192 + g * 8;
    const ushort_t* ap = Wobf + ((size_t)c0 + n) * 192 + g * 8;
    v4f acc[3];
#pragma unroll
    for (int m = 0; m < 3; ++m) acc[m] = (v4f){0.f, 0.f, 0.f, 0.f};
#pragma unroll
    for (int kk = 0; kk < 6; ++kk) {
        v8s bf = *(const v8s*)(bp + kk * 32);
#pragma unroll
        for (int m = 0; m < 3; ++m) {
            v8s af = *(const v8s*)(ap + m * 16 * 192 + kk * 32);
            acc[m] = __builtin_amdgcn_mfma_f32_16x16x32_bf16(af, bf, acc[m], 0, 0, 0);
        }
    }
    float* ob = out + (size_t)b * 96 * LL + l0 + n;
#pragma unroll
    for (int m = 0; m < 3; ++m)
#pragma unroll
        for (int r = 0; r < 4; ++r)
            ob[(size_t)(c0 + m * 16 + g * 4 + r) * LL] = acc[m][r];
}

extern "C" void kernel_launch(void* const* d_in, const int* in_sizes, int n_in,
                              void* d_out, int out_size, void* d_ws, size_t ws_size,
                              hipStream_t stream) {
    const float* x         = (const float*)d_in[0];
    const float* proj_w    = (const float*)d_in[1];
    const float* dconv_w   = (const float*)d_in[2];
    const float* in_proj_w = (const float*)d_in[3];
    const float* conv1d_w  = (const float*)d_in[4];
    const float* conv1d_b  = (const float*)d_in[5];
    const float* x_proj_w  = (const float*)d_in[6];
    const float* dt_proj_w = (const float*)d_in[7];
    const float* dt_proj_b = (const float*)d_in[8];
    const float* A_log     = (const float*)d_in[9];
    const float* Dp        = (const float*)d_in[10];
    const float* out_proj_w= (const float*)d_in[11];
    float* out = (float*)d_out;
    float* ws  = (float*)d_ws;

    // carve (float units)
    ushort_t* Wbf  = (ushort_t*)ws;                      // 82,944 sh -> 41,472 fl
    ushort_t* Wibf = (ushort_t*)(ws + 41472);            // 36,864 sh -> 18,432 fl
    ushort_t* Wobf = (ushort_t*)(ws + 59904);            // 18,432 sh ->  9,216 fl
    ushort_t* Wxbf = (ushort_t*)(ws + 69120);            //  9,216 sh ->  4,608 fl
    ushort_t* xT   = (ushort_t*)(ws + 73728);            // 1,723,392 sh -> 861,696 fl
    float* xz   = ws + 1721856;                          // 4*384*4096 = 6,291,456
    float* xc   = xz + 6291456;                          // 3,145,728
    float* dtT  = xc + 3145728;                          // 4*6*4096   =    98,304
    float* BtP  = dtT + 98304;                           // 4*4096*16  =   262,144
    float* CtP  = BtP + 262144;                          // 4*4096*16  =   262,144
    float* delta= CtP + 262144;                          // 3,145,728
    ushort_t* xcT = (ushort_t*)delta;                    // alias: dead once delta written
    // ygT aliases xz lower half per-batch (xin dead after conv1d)

    k_prep<<<dim3(576), dim3(256), 0, stream>>>(proj_w, dconv_w, in_proj_w, out_proj_w,
                                                x_proj_w, Wbf, Wibf, Wobf, Wxbf);
    k_xpad<<<dim3(66, 4), dim3(256), 0, stream>>>(x, xT);
    k_convin<<<dim3(512), dim3(384), 0, stream>>>(xT, Wbf, Wibf, xz);
    k_conv1d<<<dim3(256, 3, 4), dim3(256), 0, stream>>>(xz, conv1d_w, conv1d_b, xc, xcT);
    k_xprojm<<<dim3(64, 4), dim3(256), 0, stream>>>(xcT, Wxbf, dtT, BtP, CtP);
    k_dtproj<<<dim3(64, 4, 4), dim3(64, 4), 0, stream>>>(dtT, dt_proj_w, dt_proj_b, delta);
    k_scan<<<dim3(768), dim3(512), 0, stream>>>(delta, xc, BtP, CtP, A_log, Dp, xz);
    k_outproj<<<dim3(64, 4), dim3(512), 0, stream>>>(xz, Wobf, out);
}

// Round 10
// 115.483 us; speedup vs baseline: 1.9511x; 1.1227x over previous
//
#include <hip/hip_runtime.h>
#include <math.h>

#define LL    4096
#define CDIM  96
#define DIN   192
#define NST   16
#define XE    38   // dt_rank(6) + 2*16

typedef __attribute__((ext_vector_type(8))) short v8s;
typedef __attribute__((ext_vector_type(4))) float v4f;
typedef unsigned short ushort_t;
typedef unsigned int uint_t;

#if __has_builtin(__builtin_amdgcn_exp2f)
__device__ __forceinline__ float fexp2(float x) { return __builtin_amdgcn_exp2f(x); }
#else
__device__ __forceinline__ float fexp2(float x) { return exp2f(x); }
#endif
#if __has_builtin(__builtin_amdgcn_logf)
__device__ __forceinline__ float flog2(float x) { return __builtin_amdgcn_logf(x); }
#else
__device__ __forceinline__ float flog2(float x) { return __log2f(x); }
#endif

__device__ __forceinline__ float siluf(float x) {
    return x * __builtin_amdgcn_rcpf(1.f + fexp2(-1.44269504f * x));
}
__device__ __forceinline__ ushort_t f2bf(float f) {
    uint_t u = __builtin_bit_cast(uint_t, f);
    return (ushort_t)((u + 0x7fffu + ((u >> 16) & 1u)) >> 16);
}

// ---------------- Kernel 1: weight prep + x pad/transpose in ONE launch
__global__ __launch_bounds__(256) void k_prep(const float* __restrict__ proj_w,
                                              const float* __restrict__ dconv_w,
                                              const float* __restrict__ in_proj_w,
                                              const float* __restrict__ out_proj_w,
                                              const float* __restrict__ x_proj_w,
                                              const float* __restrict__ x,
                                              ushort_t* __restrict__ Wbf,
                                              ushort_t* __restrict__ Wibf,
                                              ushort_t* __restrict__ Wobf,
                                              ushort_t* __restrict__ Wxbf,
                                              ushort_t* __restrict__ xT) {
    int bid = blockIdx.x;
    if (bid < 576) {
        int i = bid * 256 + threadIdx.x;
        if (i < 82944) {
            int k = i % 9;
            int c = (i / 9) % 96;
            int o = i / 864;
            float s = 0.f;
            for (int j = 0; j < 192; ++j)
                s += dconv_w[(o * 192 + j) * 9 + k] * proj_w[j * 96 + c];
            Wbf[(k * 96 + o) * 96 + c] = f2bf(s);
            return;
        }
        i -= 82944;
        if (i < 36864) { Wibf[i] = f2bf(in_proj_w[i]); return; }
        i -= 36864;
        if (i < 18432) { Wobf[i] = f2bf(out_proj_w[i]); return; }
        i -= 18432;
        if (i < 9216) {
            int e = i / 192;
            Wxbf[i] = (e < XE) ? f2bf(x_proj_w[i]) : (ushort_t)0;
        }
        return;
    }
    // xpad part: x (B,96,64,64) f32 -> xT[b][66][68][96] bf16, zero halo
    int bid2 = bid - 576;
    int yy = bid2 % 66;
    int b  = bid2 / 66;
    int yv = yy - 1;
    for (int i = threadIdx.x; i < 68 * 12; i += 256) {
        int xx = i % 68, cig = i / 68;
        int xv = xx - 1;
        ushort_t u[8];
        if (yv >= 0 && yv < 64 && xv >= 0 && xv < 64) {
            const float* sp = x + ((size_t)(b * 96 + cig * 8)) * LL + yv * 64 + xv;
#pragma unroll
            for (int j = 0; j < 8; ++j) u[j] = f2bf(sp[j * LL]);
        } else {
#pragma unroll
            for (int j = 0; j < 8; ++j) u[j] = 0;
        }
        uint4 pk;
        pk.x = u[0] | ((uint_t)u[1] << 16); pk.y = u[2] | ((uint_t)u[3] << 16);
        pk.z = u[4] | ((uint_t)u[5] << 16); pk.w = u[6] | ((uint_t)u[7] << 16);
        *(uint4*)(xT + (((size_t)b * 66 + yy) * 68 + xx) * 96 + cig * 8) = pk;
    }
}

// ---------------- Kernel 2: FUSED 3x3-conv + in_proj via MFMA -> xz[b][e][l] f32
__global__ __launch_bounds__(384, 2) void k_convin(const ushort_t* __restrict__ xT,
                                                   const ushort_t* __restrict__ Wbf,
                                                   const ushort_t* __restrict__ Wibf,
                                                   float* __restrict__ xz) {
    __shared__ ushort_t s_seq[32 * 104];
    int tid = threadIdx.x;
    int w = tid >> 6, l = tid & 63;
    int n = l & 15, g = l >> 4;
    int blk = blockIdx.x;
    int b = blk >> 7, rem = blk & 127;
    int y = rem >> 1, half = rem & 1;
    int lx = (w & 1) * 16;
    int x0 = half * 32 + lx;
    int co0 = (w >> 1) * 32;
    v4f acc0 = {0.f, 0.f, 0.f, 0.f};
    v4f acc1 = {0.f, 0.f, 0.f, 0.f};
    const ushort_t* xb = xT + (((size_t)b * 66 + y) * 68 + x0 + n) * 96 + g * 8;
    const ushort_t* aw = Wbf + ((size_t)co0 + n) * 96 + g * 8;
#pragma unroll
    for (int tap = 0; tap < 9; ++tap) {
        int dy = tap / 3, dx = tap % 3;
        const ushort_t* bp = xb + (dy * 68 + dx) * 96;
        const ushort_t* ap = aw + (size_t)tap * 9216;
#pragma unroll
        for (int kk = 0; kk < 3; ++kk) {
            v8s bf = *(const v8s*)(bp + kk * 32);
            v8s a0 = *(const v8s*)(ap + kk * 32);
            v8s a1 = *(const v8s*)(ap + 1536 + kk * 32);
            acc0 = __builtin_amdgcn_mfma_f32_16x16x32_bf16(a0, bf, acc0, 0, 0, 0);
            acc1 = __builtin_amdgcn_mfma_f32_16x16x32_bf16(a1, bf, acc1, 0, 0, 0);
        }
    }
    {
        int ll = lx + n;
        ushort_t* sp = s_seq + ll * 104 + co0 + g * 4;
        ushort4 p0, p1;
        p0.x = f2bf(acc0[0]); p0.y = f2bf(acc0[1]); p0.z = f2bf(acc0[2]); p0.w = f2bf(acc0[3]);
        p1.x = f2bf(acc1[0]); p1.y = f2bf(acc1[1]); p1.z = f2bf(acc1[2]); p1.w = f2bf(acc1[3]);
        *(ushort4*)sp = p0;
        *(ushort4*)(sp + 16) = p1;
    }
    __syncthreads();
    int coh = w * 64;
    v4f acc[4][2];
#pragma unroll
    for (int mt = 0; mt < 4; ++mt)
#pragma unroll
        for (int lt = 0; lt < 2; ++lt) acc[mt][lt] = (v4f){0.f, 0.f, 0.f, 0.f};
    const ushort_t* ap2 = Wibf + ((size_t)coh + n) * 96 + g * 8;
#pragma unroll
    for (int lt = 0; lt < 2; ++lt) {
        const ushort_t* bp2 = s_seq + (lt * 16 + n) * 104 + g * 8;
#pragma unroll
        for (int kk = 0; kk < 3; ++kk) {
            v8s bf = *(const v8s*)(bp2 + kk * 32);
#pragma unroll
            for (int mt = 0; mt < 4; ++mt) {
                v8s af = *(const v8s*)(ap2 + mt * 16 * 96 + kk * 32);
                acc[mt][lt] = __builtin_amdgcn_mfma_f32_16x16x32_bf16(af, bf, acc[mt][lt], 0, 0, 0);
            }
        }
    }
    int l0g = y * 64 + half * 32;
    float* ob = xz + (size_t)b * 384 * LL + l0g + n;
#pragma unroll
    for (int mt = 0; mt < 4; ++mt) {
        int e = coh + mt * 16 + g * 4;
#pragma unroll
        for (int lt = 0; lt < 2; ++lt)
#pragma unroll
            for (int r = 0; r < 4; ++r)
                ob[(size_t)(e + r) * LL + lt * 16] = acc[mt][lt][r];
    }
}

// ---------------- Kernel 3: causal depthwise conv1d (k=4) + SiLU -> xc f32 + xcT bf16
__global__ __launch_bounds__(256) void k_conv1d(const float* __restrict__ xz,
                                                const float* __restrict__ w,
                                                const float* __restrict__ bias,
                                                float* __restrict__ xc,
                                                ushort_t* __restrict__ xcT) {
    int tid = threadIdx.x;
    int d_l = tid >> 2, tg = tid & 3;
    int b = blockIdx.z, dg = blockIdx.y, tt = blockIdx.x;
    int d = dg * 64 + d_l;
    int t0 = tt * 16 + tg * 4;
    const float* xin = xz + (size_t)(b * 384 + d) * LL;
    float4 cur = *(const float4*)(xin + t0);
    float pm3 = 0.f, pm2 = 0.f, pm1 = 0.f;
    if (t0 > 0) {
        float4 prev = *(const float4*)(xin + t0 - 4);
        pm3 = prev.y; pm2 = prev.z; pm1 = prev.w;
    }
    float in[7] = {pm3, pm2, pm1, cur.x, cur.y, cur.z, cur.w};
    float w0 = w[d * 4 + 0], w1 = w[d * 4 + 1], w2 = w[d * 4 + 2], w3 = w[d * 4 + 3];
    float bb = bias[d];
    float o[4];
#pragma unroll
    for (int i = 0; i < 4; ++i) {
        float s = bb + w0 * in[i] + w1 * in[i + 1] + w2 * in[i + 2] + w3 * in[i + 3];
        o[i] = siluf(s);
    }
    float4 ov; ov.x = o[0]; ov.y = o[1]; ov.z = o[2]; ov.w = o[3];
    *(float4*)(xc + (size_t)(b * DIN + d) * LL + t0) = ov;
    ushort_t* xt = xcT + ((size_t)b * 4096 + t0) * DIN + d;
#pragma unroll
    for (int i = 0; i < 4; ++i)
        xt[(size_t)i * DIN] = f2bf(o[i]);
}

// ---------------- Kernel 4: x_proj via MFMA -> dtT [r][t]; BtP/CtP packed [t][16]
__global__ __launch_bounds__(256, 4) void k_xprojm(const ushort_t* __restrict__ xcT,
                                                   const ushort_t* __restrict__ Wxbf,
                                                   float* __restrict__ dtT,
                                                   float* __restrict__ BtP,
                                                   float* __restrict__ CtP) {
    int tid = threadIdx.x;
    int w = tid >> 6, l = tid & 63;
    int n = l & 15, g = l >> 4;
    int b = blockIdx.y;
    int l0 = blockIdx.x * 64 + w * 16;
    const ushort_t* bp = xcT + ((size_t)b * 4096 + l0 + n) * 192 + g * 8;
    const ushort_t* ap = Wxbf + (size_t)n * 192 + g * 8;
    v4f acc[3];
#pragma unroll
    for (int m = 0; m < 3; ++m) acc[m] = (v4f){0.f, 0.f, 0.f, 0.f};
#pragma unroll
    for (int kk = 0; kk < 6; ++kk) {
        v8s bf = *(const v8s*)(bp + kk * 32);
#pragma unroll
        for (int m = 0; m < 3; ++m) {
            v8s af = *(const v8s*)(ap + m * 16 * 192 + kk * 32);
            acc[m] = __builtin_amdgcn_mfma_f32_16x16x32_bf16(af, bf, acc[m], 0, 0, 0);
        }
    }
    float* dtb = dtT + (size_t)b * 6 * LL + l0 + n;
    float* Bb = BtP + ((size_t)b * LL + l0 + n) * 16;
    float* Cb = CtP + ((size_t)b * LL + l0 + n) * 16;
#pragma unroll
    for (int m = 0; m < 3; ++m)
#pragma unroll
        for (int r = 0; r < 4; ++r) {
            int e = m * 16 + g * 4 + r;
            float v = acc[m][r];
            if (e < 6)       dtb[(size_t)e * LL] = v;
            else if (e < 22) Bb[e - 6] = v;
            else if (e < 38) Cb[e - 22] = v;
        }
}

// ---------------- Kernel 5: selective scan (fused dt_proj+softplus) -> yg[d][t] bf16
__global__ __launch_bounds__(512, 6) void k_scan(const float* __restrict__ dtT,
                                                 const float* __restrict__ dtw,
                                                 const float* __restrict__ dtpb,
                                                 const float* __restrict__ xc,
                                                 const float* __restrict__ BtP,
                                                 const float* __restrict__ CtP,
                                                 const float* __restrict__ A_log,
                                                 const float* __restrict__ Dp,
                                                 float* __restrict__ xz) {
    __shared__ float s_d[32 * 132];       // chunk c at c*132 (+4 pad)
    __shared__ float s_u[32 * 132];
    __shared__ float s_a[32][17];
    __shared__ float s_h[32][17];
    int tid = threadIdx.x;
    int n = tid & 15, cg = tid >> 4;      // 32 chunks x 16 states
    int bd = blockIdx.x;
    int d = bd % DIN, b = bd / DIN;
    const float* urow = xc + (size_t)(b * DIN + d) * LL;
    const float* zrow = xz + (size_t)(b * 384 + DIN + d) * LL;
    ushort_t* ygr     = (ushort_t*)(xz + (size_t)b * 384 * LL) + (size_t)d * LL;
    float A2 = -__expf(A_log[d * NST + n]) * 1.44269504f;   // for fexp2
    float Dd = Dp[d];

    // ---- staging: delta = softplus(dt_proj) computed in-kernel; u loaded
    {
        int t8 = tid * 8;
        int li = ((t8 >> 7) * 132) + (t8 & 127);
        const float* dt0 = dtT + (size_t)b * 6 * LL + t8;
        v4f ra[6], rb[6];
#pragma unroll
        for (int r = 0; r < 6; ++r) {
            ra[r] = *(const v4f*)(dt0 + r * LL);
            rb[r] = *(const v4f*)(dt0 + r * LL + 4);
        }
        const float* wr = dtw + d * 6;    // block-uniform -> scalar loads
        float w0 = wr[0], w1 = wr[1], w2 = wr[2], w3 = wr[3], w4 = wr[4], w5 = wr[5];
        float bb = dtpb[d];
        v4f spa, spb;
#pragma unroll
        for (int j = 0; j < 4; ++j) {
            float s1 = bb + w0 * ra[0][j] + w1 * ra[1][j] + w2 * ra[2][j]
                          + w3 * ra[3][j] + w4 * ra[4][j] + w5 * ra[5][j];
            spa[j] = 0.69314718f * flog2(1.f + fexp2(s1 * 1.44269504f));
            float s2 = bb + w0 * rb[0][j] + w1 * rb[1][j] + w2 * rb[2][j]
                          + w3 * rb[3][j] + w4 * rb[4][j] + w5 * rb[5][j];
            spb[j] = 0.69314718f * flog2(1.f + fexp2(s2 * 1.44269504f));
        }
        *(v4f*)&s_d[li]     = spa;
        *(v4f*)&s_d[li + 4] = spb;
        *(float4*)&s_u[li]     = *(const float4*)(urow + t8);
        *(float4*)&s_u[li + 4] = *(const float4*)(urow + t8 + 4);
    }
    __syncthreads();

    int t0 = cg * 128;
    int lb = cg * 132;
    const float* pB = BtP + ((size_t)b * LL + t0) * 16 + n;
    const float* pC = CtP + ((size_t)b * LL + t0) * 16 + n;

    // ---- phase 1: per-chunk aggregates; aP in log space
    float h = 0.f, sdu = 0.f;
    float4 du_c = *(float4*)&s_d[lb];
    float4 u_c  = *(float4*)&s_u[lb];
    float B0 = pB[0], B1 = pB[16], B2 = pB[32], B3 = pB[48];
    for (int s = 0; s < 31; ++s) {
        int ln = lb + s * 4 + 4;
        const float* pBn = pB + s * 64 + 64;
        float4 du_n = *(float4*)&s_d[ln];
        float4 u_n  = *(float4*)&s_u[ln];
        float Bn0 = pBn[0], Bn1 = pBn[16], Bn2 = pBn[32], Bn3 = pBn[48];
        float a0 = fexp2(du_c.x * A2), a1 = fexp2(du_c.y * A2);
        float a2 = fexp2(du_c.z * A2), a3 = fexp2(du_c.w * A2);
        h = fmaf(a0, h, (du_c.x * u_c.x) * B0);
        h = fmaf(a1, h, (du_c.y * u_c.y) * B1);
        h = fmaf(a2, h, (du_c.z * u_c.z) * B2);
        h = fmaf(a3, h, (du_c.w * u_c.w) * B3);
        sdu += (du_c.x + du_c.y) + (du_c.z + du_c.w);
        du_c = du_n; u_c = u_n; B0 = Bn0; B1 = Bn1; B2 = Bn2; B3 = Bn3;
    }
    {
        float a0 = fexp2(du_c.x * A2), a1 = fexp2(du_c.y * A2);
        float a2 = fexp2(du_c.z * A2), a3 = fexp2(du_c.w * A2);
        h = fmaf(a0, h, (du_c.x * u_c.x) * B0);
        h = fmaf(a1, h, (du_c.y * u_c.y) * B1);
        h = fmaf(a2, h, (du_c.z * u_c.z) * B2);
        h = fmaf(a3, h, (du_c.w * u_c.w) * B3);
        sdu += (du_c.x + du_c.y) + (du_c.z + du_c.w);
    }
    s_a[cg][n] = fexp2(sdu * A2);
    s_h[cg][n] = h;
    __syncthreads();

    // ---- phase 2: Kogge-Stone scan of 32 chunk aggregates (per n)
    {
        int l = tid & 63, w = tid >> 6;
        int c = l & 31, nn = (w << 1) | (l >> 5);
        float a  = s_a[c][nn];
        float hh = s_h[c][nn];
#pragma unroll
        for (int st = 1; st < 32; st <<= 1) {
            float ap = __shfl_up(a, st, 32);
            float hp = __shfl_up(hh, st, 32);
            bool ok = (c >= st);
            hh = ok ? fmaf(a, hp, hh) : hh;
            a  = ok ? a * ap : a;
        }
        float h0 = __shfl_up(hh, 1, 32);
        if (c == 0) h0 = 0.f;
        s_a[c][nn] = h0;
    }
    __syncthreads();

    // ---- phase 3: recompute with h0; partial-butterfly reduce; lane-t epilogue
    h = s_a[cg][n];
    const int j = n & 3;
    const bool e1 = (j == 1), e2 = (j == 2), e3 = (j == 3);
    du_c = *(float4*)&s_d[lb];
    u_c  = *(float4*)&s_u[lb];
    B0 = pB[0]; B1 = pB[16]; B2 = pB[32]; B3 = pB[48];
    float C0 = pC[0], C1 = pC[16], C2 = pC[32], C3 = pC[48];
    float4 z_c = *(const float4*)(zrow + t0);
    for (int s = 0; s < 32; ++s) {
        float4 du_n, u_n, z_n;
        float Bn0, Bn1, Bn2, Bn3, Cn0, Cn1, Cn2, Cn3;
        if (s < 31) {
            int ln = lb + s * 4 + 4;
            const float* pBn = pB + s * 64 + 64;
            const float* pCn = pC + s * 64 + 64;
            du_n = *(float4*)&s_d[ln];
            u_n  = *(float4*)&s_u[ln];
            Bn0 = pBn[0]; Bn1 = pBn[16]; Bn2 = pBn[32]; Bn3 = pBn[48];
            Cn0 = pCn[0]; Cn1 = pCn[16]; Cn2 = pCn[32]; Cn3 = pCn[48];
            z_n = *(const float4*)(zrow + t0 + s * 4 + 4);
        }
        float a0 = fexp2(du_c.x * A2), a1 = fexp2(du_c.y * A2);
        float a2 = fexp2(du_c.z * A2), a3 = fexp2(du_c.w * A2);
        h = fmaf(a0, h, (du_c.x * u_c.x) * B0); float p0 = h * C0;
        h = fmaf(a1, h, (du_c.y * u_c.y) * B1); float p1 = h * C1;
        h = fmaf(a2, h, (du_c.z * u_c.z) * B2); float p2 = h * C2;
        h = fmaf(a3, h, (du_c.w * u_c.w) * B3); float p3 = h * C3;
        p0 += __shfl_xor(p0, 1); p0 += __shfl_xor(p0, 2);
        p1 += __shfl_xor(p1, 1); p1 += __shfl_xor(p1, 2);
        p2 += __shfl_xor(p2, 1); p2 += __shfl_xor(p2, 2);
        p3 += __shfl_xor(p3, 1); p3 += __shfl_xor(p3, 2);
        float pj = e3 ? p3 : (e2 ? p2 : (e1 ? p1 : p0));
        pj += __shfl_xor(pj, 4); pj += __shfl_xor(pj, 8);
        float uj = e3 ? u_c.w : (e2 ? u_c.z : (e1 ? u_c.y : u_c.x));
        float zj = e3 ? z_c.w : (e2 ? z_c.z : (e1 ? z_c.y : z_c.x));
        float yj = fmaf(Dd, uj, pj) * siluf(zj);
        if (n < 4)
            ygr[t0 + s * 4 + n] = f2bf(yj);   // row-major [d][t]: contiguous per block
        du_c = du_n; u_c = u_n; z_c = z_n;
        B0 = Bn0; B1 = Bn1; B2 = Bn2; B3 = Bn3;
        C0 = Cn0; C1 = Cn1; C2 = Cn2; C3 = Cn3;
    }
}

// ---------------- Kernel 6: out_proj via MFMA with LDS transpose of yg[d][t]
__global__ __launch_bounds__(512, 2) void k_outproj(const float* __restrict__ xzBase,
                                                    const ushort_t* __restrict__ Wobf,
                                                    float* __restrict__ out) {
    __shared__ ushort_t s_yg[64][216];    // [l_local][d], pad 216 (16B-aligned rows, 2-way banks)
    int tid = threadIdx.x;
    int b = blockIdx.y;
    int l0 = blockIdx.x * 64;
    const ushort_t* ygb = (const ushort_t*)(xzBase + (size_t)b * 384 * LL);
    // stage + transpose: 48 d-quads x 8 t-octets
    {
        int q = tid & 63, o = tid >> 6;
        if (q < 48) {
            uint4 v[4];
#pragma unroll
            for (int jj = 0; jj < 4; ++jj)
                v[jj] = *(const uint4*)(ygb + (size_t)(q * 4 + jj) * LL + l0 + o * 8);
            const ushort_t* vs = (const ushort_t*)v;
#pragma unroll
            for (int j2 = 0; j2 < 8; ++j2) {
                ushort4 pk;
                pk.x = vs[j2]; pk.y = vs[8 + j2]; pk.z = vs[16 + j2]; pk.w = vs[24 + j2];
                *(ushort4*)&s_yg[o * 8 + j2][q * 4] = pk;
            }
        }
    }
    __syncthreads();
    int w = tid >> 6, l = tid & 63;
    int n = l & 15, g = l >> 4;
    int lt = (w >> 1) * 16;
    int c0 = (w & 1) * 48;
    const ushort_t* bp = &s_yg[lt + n][g * 8];
    const ushort_t* ap = Wobf + ((size_t)c0 + n) * 192 + g * 8;
    v4f acc[3];
#pragma unroll
    for (int m = 0; m < 3; ++m) acc[m] = (v4f){0.f, 0.f, 0.f, 0.f};
#pragma unroll
    for (int kk = 0; kk < 6; ++kk) {
        v8s bf = *(const v8s*)(bp + kk * 32);
#pragma unroll
        for (int m = 0; m < 3; ++m) {
            v8s af = *(const v8s*)(ap + m * 16 * 192 + kk * 32);
            acc[m] = __builtin_amdgcn_mfma_f32_16x16x32_bf16(af, bf, acc[m], 0, 0, 0);
        }
    }
    float* ob = out + (size_t)b * 96 * LL + l0 + lt + n;
#pragma unroll
    for (int m = 0; m < 3; ++m)
#pragma unroll
        for (int r = 0; r < 4; ++r)
            ob[(size_t)(c0 + m * 16 + g * 4 + r) * LL] = acc[m][r];
}

extern "C" void kernel_launch(void* const* d_in, const int* in_sizes, int n_in,
                              void* d_out, int out_size, void* d_ws, size_t ws_size,
                              hipStream_t stream) {
    const float* x         = (const float*)d_in[0];
    const float* proj_w    = (const float*)d_in[1];
    const float* dconv_w   = (const float*)d_in[2];
    const float* in_proj_w = (const float*)d_in[3];
    const float* conv1d_w  = (const float*)d_in[4];
    const float* conv1d_b  = (const float*)d_in[5];
    const float* x_proj_w  = (const float*)d_in[6];
    const float* dt_proj_w = (const float*)d_in[7];
    const float* dt_proj_b = (const float*)d_in[8];
    const float* A_log     = (const float*)d_in[9];
    const float* Dp        = (const float*)d_in[10];
    const float* out_proj_w= (const float*)d_in[11];
    float* out = (float*)d_out;
    float* ws  = (float*)d_ws;

    // carve (float units)
    ushort_t* Wbf  = (ushort_t*)ws;                      // 82,944 sh -> 41,472 fl
    ushort_t* Wibf = (ushort_t*)(ws + 41472);            // 36,864 sh -> 18,432 fl
    ushort_t* Wobf = (ushort_t*)(ws + 59904);            // 18,432 sh ->  9,216 fl
    ushort_t* Wxbf = (ushort_t*)(ws + 69120);            //  9,216 sh ->  4,608 fl
    ushort_t* xT   = (ushort_t*)(ws + 73728);            // 1,723,392 sh -> 861,696 fl
    float* xz   = ws + 1721856;                          // 4*384*4096 = 6,291,456
    float* xc   = xz + 6291456;                          // 3,145,728
    float* dtT  = xc + 3145728;                          // 4*6*4096   =    98,304
    float* BtP  = dtT + 98304;                           // 4*4096*16  =   262,144
    float* CtP  = BtP + 262144;                          // 4*4096*16  =   262,144
    ushort_t* xcT = (ushort_t*)(CtP + 262144);           // 4*4096*192 bf16
    // yg[d][t] bf16 aliases xz lower (xin) half per-batch (dead after conv1d)

    k_prep<<<dim3(840), dim3(256), 0, stream>>>(proj_w, dconv_w, in_proj_w, out_proj_w,
                                                x_proj_w, x, Wbf, Wibf, Wobf, Wxbf, xT);
    k_convin<<<dim3(512), dim3(384), 0, stream>>>(xT, Wbf, Wibf, xz);
    k_conv1d<<<dim3(256, 3, 4), dim3(256), 0, stream>>>(xz, conv1d_w, conv1d_b, xc, xcT);
    k_xprojm<<<dim3(64, 4), dim3(256), 0, stream>>>(xcT, Wxbf, dtT, BtP, CtP);
    k_scan<<<dim3(768), dim3(512), 0, stream>>>(dtT, dt_proj_w, dt_proj_b, xc, BtP, CtP,
                                                A_log, Dp, xz);
    k_outproj<<<dim3(64, 4), dim3(512), 0, stream>>>(xz, Wobf, out);
}

// Round 11
// 114.939 us; speedup vs baseline: 1.9603x; 1.0047x over previous
//
#include <hip/hip_runtime.h>
#include <math.h>

#define LL    4096
#define CDIM  96
#define DIN   192
#define NST   16
#define XE    38   // dt_rank(6) + 2*16

typedef __attribute__((ext_vector_type(8))) short v8s;
typedef __attribute__((ext_vector_type(4))) float v4f;
typedef unsigned short ushort_t;
typedef unsigned int uint_t;

#if __has_builtin(__builtin_amdgcn_exp2f)
__device__ __forceinline__ float fexp2(float x) { return __builtin_amdgcn_exp2f(x); }
#else
__device__ __forceinline__ float fexp2(float x) { return exp2f(x); }
#endif
#if __has_builtin(__builtin_amdgcn_logf)
__device__ __forceinline__ float flog2(float x) { return __builtin_amdgcn_logf(x); }
#else
__device__ __forceinline__ float flog2(float x) { return __log2f(x); }
#endif

__device__ __forceinline__ float siluf(float x) {
    return x * __builtin_amdgcn_rcpf(1.f + fexp2(-1.44269504f * x));
}
__device__ __forceinline__ ushort_t f2bf(float f) {
    uint_t u = __builtin_bit_cast(uint_t, f);
    return (ushort_t)((u + 0x7fffu + ((u >> 16) & 1u)) >> 16);
}
__device__ __forceinline__ float bf2f(ushort_t u) {
    return __builtin_bit_cast(float, (uint_t)u << 16);
}

// ---------------- Kernel 1: weight prep + x pad/transpose in ONE launch
__global__ __launch_bounds__(256) void k_prep(const float* __restrict__ proj_w,
                                              const float* __restrict__ dconv_w,
                                              const float* __restrict__ in_proj_w,
                                              const float* __restrict__ out_proj_w,
                                              const float* __restrict__ x_proj_w,
                                              const float* __restrict__ x,
                                              ushort_t* __restrict__ Wbf,
                                              ushort_t* __restrict__ Wibf,
                                              ushort_t* __restrict__ Wobf,
                                              ushort_t* __restrict__ Wxbf,
                                              ushort_t* __restrict__ xT) {
    int bid = blockIdx.x;
    if (bid < 576) {
        int i = bid * 256 + threadIdx.x;
        if (i < 82944) {
            int k = i % 9;
            int c = (i / 9) % 96;
            int o = i / 864;
            float s = 0.f;
            for (int j = 0; j < 192; ++j)
                s += dconv_w[(o * 192 + j) * 9 + k] * proj_w[j * 96 + c];
            Wbf[(k * 96 + o) * 96 + c] = f2bf(s);
            return;
        }
        i -= 82944;
        if (i < 36864) { Wibf[i] = f2bf(in_proj_w[i]); return; }
        i -= 36864;
        if (i < 18432) { Wobf[i] = f2bf(out_proj_w[i]); return; }
        i -= 18432;
        if (i < 9216) {
            int e = i / 192;
            Wxbf[i] = (e < XE) ? f2bf(x_proj_w[i]) : (ushort_t)0;
        }
        return;
    }
    int bid2 = bid - 576;
    int yy = bid2 % 66;
    int b  = bid2 / 66;
    int yv = yy - 1;
    for (int i = threadIdx.x; i < 68 * 12; i += 256) {
        int xx = i % 68, cig = i / 68;
        int xv = xx - 1;
        ushort_t u[8];
        if (yv >= 0 && yv < 64 && xv >= 0 && xv < 64) {
            const float* sp = x + ((size_t)(b * 96 + cig * 8)) * LL + yv * 64 + xv;
#pragma unroll
            for (int j = 0; j < 8; ++j) u[j] = f2bf(sp[j * LL]);
        } else {
#pragma unroll
            for (int j = 0; j < 8; ++j) u[j] = 0;
        }
        uint4 pk;
        pk.x = u[0] | ((uint_t)u[1] << 16); pk.y = u[2] | ((uint_t)u[3] << 16);
        pk.z = u[4] | ((uint_t)u[5] << 16); pk.w = u[6] | ((uint_t)u[7] << 16);
        *(uint4*)(xT + (((size_t)b * 66 + yy) * 68 + xx) * 96 + cig * 8) = pk;
    }
}

// ---------------- Kernel 2: FUSED 3x3-conv + in_proj via MFMA -> xzb[b][e][l] bf16
__global__ __launch_bounds__(384, 2) void k_convin(const ushort_t* __restrict__ xT,
                                                   const ushort_t* __restrict__ Wbf,
                                                   const ushort_t* __restrict__ Wibf,
                                                   ushort_t* __restrict__ xzb) {
    __shared__ ushort_t s_seq[32 * 104];
    int tid = threadIdx.x;
    int w = tid >> 6, l = tid & 63;
    int n = l & 15, g = l >> 4;
    int blk = blockIdx.x;
    int b = blk >> 7, rem = blk & 127;
    int y = rem >> 1, half = rem & 1;
    int lx = (w & 1) * 16;
    int x0 = half * 32 + lx;
    int co0 = (w >> 1) * 32;
    v4f acc0 = {0.f, 0.f, 0.f, 0.f};
    v4f acc1 = {0.f, 0.f, 0.f, 0.f};
    const ushort_t* xb = xT + (((size_t)b * 66 + y) * 68 + x0 + n) * 96 + g * 8;
    const ushort_t* aw = Wbf + ((size_t)co0 + n) * 96 + g * 8;
#pragma unroll
    for (int tap = 0; tap < 9; ++tap) {
        int dy = tap / 3, dx = tap % 3;
        const ushort_t* bp = xb + (dy * 68 + dx) * 96;
        const ushort_t* ap = aw + (size_t)tap * 9216;
#pragma unroll
        for (int kk = 0; kk < 3; ++kk) {
            v8s bf = *(const v8s*)(bp + kk * 32);
            v8s a0 = *(const v8s*)(ap + kk * 32);
            v8s a1 = *(const v8s*)(ap + 1536 + kk * 32);
            acc0 = __builtin_amdgcn_mfma_f32_16x16x32_bf16(a0, bf, acc0, 0, 0, 0);
            acc1 = __builtin_amdgcn_mfma_f32_16x16x32_bf16(a1, bf, acc1, 0, 0, 0);
        }
    }
    {
        int ll = lx + n;
        ushort_t* sp = s_seq + ll * 104 + co0 + g * 4;
        ushort4 p0, p1;
        p0.x = f2bf(acc0[0]); p0.y = f2bf(acc0[1]); p0.z = f2bf(acc0[2]); p0.w = f2bf(acc0[3]);
        p1.x = f2bf(acc1[0]); p1.y = f2bf(acc1[1]); p1.z = f2bf(acc1[2]); p1.w = f2bf(acc1[3]);
        *(ushort4*)sp = p0;
        *(ushort4*)(sp + 16) = p1;
    }
    __syncthreads();
    int coh = w * 64;
    v4f acc[4][2];
#pragma unroll
    for (int mt = 0; mt < 4; ++mt)
#pragma unroll
        for (int lt = 0; lt < 2; ++lt) acc[mt][lt] = (v4f){0.f, 0.f, 0.f, 0.f};
    const ushort_t* ap2 = Wibf + ((size_t)coh + n) * 96 + g * 8;
#pragma unroll
    for (int lt = 0; lt < 2; ++lt) {
        const ushort_t* bp2 = s_seq + (lt * 16 + n) * 104 + g * 8;
#pragma unroll
        for (int kk = 0; kk < 3; ++kk) {
            v8s bf = *(const v8s*)(bp2 + kk * 32);
#pragma unroll
            for (int mt = 0; mt < 4; ++mt) {
                v8s af = *(const v8s*)(ap2 + mt * 16 * 96 + kk * 32);
                acc[mt][lt] = __builtin_amdgcn_mfma_f32_16x16x32_bf16(af, bf, acc[mt][lt], 0, 0, 0);
            }
        }
    }
    int l0g = y * 64 + half * 32;
    ushort_t* ob = xzb + (size_t)b * 384 * LL + l0g + n;
#pragma unroll
    for (int mt = 0; mt < 4; ++mt) {
        int e = coh + mt * 16 + g * 4;
#pragma unroll
        for (int lt = 0; lt < 2; ++lt)
#pragma unroll
            for (int r = 0; r < 4; ++r)
                ob[(size_t)(e + r) * LL + lt * 16] = f2bf(acc[mt][lt][r]);
    }
}

// ---------------- Kernel 3: causal depthwise conv1d (k=4) + SiLU -> xc f32 + xcT bf16
__global__ __launch_bounds__(256) void k_conv1d(const ushort_t* __restrict__ xzb,
                                                const float* __restrict__ w,
                                                const float* __restrict__ bias,
                                                float* __restrict__ xc,
                                                ushort_t* __restrict__ xcT) {
    int tid = threadIdx.x;
    int d_l = tid >> 2, tg = tid & 3;
    int b = blockIdx.z, dg = blockIdx.y, tt = blockIdx.x;
    int d = dg * 64 + d_l;
    int t0 = tt * 16 + tg * 4;
    const ushort_t* xin = xzb + (size_t)(b * 384 + d) * LL;
    ushort4 cu = *(const ushort4*)(xin + t0);
    float pm3 = 0.f, pm2 = 0.f, pm1 = 0.f;
    if (t0 > 0) {
        ushort4 pv = *(const ushort4*)(xin + t0 - 4);
        pm3 = bf2f(pv.y); pm2 = bf2f(pv.z); pm1 = bf2f(pv.w);
    }
    float in[7] = {pm3, pm2, pm1, bf2f(cu.x), bf2f(cu.y), bf2f(cu.z), bf2f(cu.w)};
    float w0 = w[d * 4 + 0], w1 = w[d * 4 + 1], w2 = w[d * 4 + 2], w3 = w[d * 4 + 3];
    float bb = bias[d];
    float o[4];
#pragma unroll
    for (int i = 0; i < 4; ++i) {
        float s = bb + w0 * in[i] + w1 * in[i + 1] + w2 * in[i + 2] + w3 * in[i + 3];
        o[i] = siluf(s);
    }
    float4 ov; ov.x = o[0]; ov.y = o[1]; ov.z = o[2]; ov.w = o[3];
    *(float4*)(xc + (size_t)(b * DIN + d) * LL + t0) = ov;
    ushort_t* xt = xcT + ((size_t)b * 4096 + t0) * DIN + d;
#pragma unroll
    for (int i = 0; i < 4; ++i)
        xt[(size_t)i * DIN] = f2bf(o[i]);
}

// ---------------- Kernel 4: x_proj via MFMA -> dtT [r][t]; BtP/CtP packed [t][16]
__global__ __launch_bounds__(256, 4) void k_xprojm(const ushort_t* __restrict__ xcT,
                                                   const ushort_t* __restrict__ Wxbf,
                                                   float* __restrict__ dtT,
                                                   float* __restrict__ BtP,
                                                   float* __restrict__ CtP) {
    int tid = threadIdx.x;
    int w = tid >> 6, l = tid & 63;
    int n = l & 15, g = l >> 4;
    int b = blockIdx.y;
    int l0 = blockIdx.x * 64 + w * 16;
    const ushort_t* bp = xcT + ((size_t)b * 4096 + l0 + n) * 192 + g * 8;
    const ushort_t* ap = Wxbf + (size_t)n * 192 + g * 8;
    v4f acc[3];
#pragma unroll
    for (int m = 0; m < 3; ++m) acc[m] = (v4f){0.f, 0.f, 0.f, 0.f};
#pragma unroll
    for (int kk = 0; kk < 6; ++kk) {
        v8s bf = *(const v8s*)(bp + kk * 32);
#pragma unroll
        for (int m = 0; m < 3; ++m) {
            v8s af = *(const v8s*)(ap + m * 16 * 192 + kk * 32);
            acc[m] = __builtin_amdgcn_mfma_f32_16x16x32_bf16(af, bf, acc[m], 0, 0, 0);
        }
    }
    float* dtb = dtT + (size_t)b * 6 * LL + l0 + n;
    float* Bb = BtP + ((size_t)b * LL + l0 + n) * 16;
    float* Cb = CtP + ((size_t)b * LL + l0 + n) * 16;
#pragma unroll
    for (int m = 0; m < 3; ++m)
#pragma unroll
        for (int r = 0; r < 4; ++r) {
            int e = m * 16 + g * 4 + r;
            float v = acc[m][r];
            if (e < 6)       dtb[(size_t)e * LL] = v;
            else if (e < 22) Bb[e - 6] = v;
            else if (e < 38) Cb[e - 22] = v;
        }
}

// ---------------- Kernel 5: selective scan (fused dt_proj+softplus) -> yg[d][t] bf16
__global__ __launch_bounds__(512, 6) void k_scan(const float* __restrict__ dtT,
                                                 const float* __restrict__ dtw,
                                                 const float* __restrict__ dtpb,
                                                 const float* __restrict__ xc,
                                                 const float* __restrict__ BtP,
                                                 const float* __restrict__ CtP,
                                                 const float* __restrict__ A_log,
                                                 const float* __restrict__ Dp,
                                                 ushort_t* __restrict__ xzb) {
    __shared__ float s_d[32 * 132];       // chunk c at c*132 (+4 pad)
    __shared__ float s_u[32 * 132];
    __shared__ float s_a[32][17];
    __shared__ float s_h[32][17];
    int tid = threadIdx.x;
    int n = tid & 15, cg = tid >> 4;      // 32 chunks x 16 states
    int bd = blockIdx.x;
    int d = bd % DIN, b = bd / DIN;
    const float* urow = xc + (size_t)(b * DIN + d) * LL;
    const ushort_t* zrow = xzb + (size_t)(b * 384 + DIN + d) * LL;
    ushort_t* ygr = xzb + (size_t)(b * 384 + d) * LL;    // overwrites dead xin row
    float A2 = -__expf(A_log[d * NST + n]) * 1.44269504f;   // for fexp2
    float Dd = Dp[d];

    // ---- staging: delta = softplus(dt_proj) computed in-kernel; u loaded
    {
        int t8 = tid * 8;
        int li = ((t8 >> 7) * 132) + (t8 & 127);
        const float* dt0 = dtT + (size_t)b * 6 * LL + t8;
        v4f ra[6], rb[6];
#pragma unroll
        for (int r = 0; r < 6; ++r) {
            ra[r] = *(const v4f*)(dt0 + r * LL);
            rb[r] = *(const v4f*)(dt0 + r * LL + 4);
        }
        const float* wr = dtw + d * 6;    // block-uniform -> scalar loads
        float w0 = wr[0], w1 = wr[1], w2 = wr[2], w3 = wr[3], w4 = wr[4], w5 = wr[5];
        float bb = dtpb[d];
        v4f spa, spb;
#pragma unroll
        for (int j = 0; j < 4; ++j) {
            float s1 = bb + w0 * ra[0][j] + w1 * ra[1][j] + w2 * ra[2][j]
                          + w3 * ra[3][j] + w4 * ra[4][j] + w5 * ra[5][j];
            spa[j] = 0.69314718f * flog2(1.f + fexp2(s1 * 1.44269504f));
            float s2 = bb + w0 * rb[0][j] + w1 * rb[1][j] + w2 * rb[2][j]
                          + w3 * rb[3][j] + w4 * rb[4][j] + w5 * rb[5][j];
            spb[j] = 0.69314718f * flog2(1.f + fexp2(s2 * 1.44269504f));
        }
        *(v4f*)&s_d[li]     = spa;
        *(v4f*)&s_d[li + 4] = spb;
        *(float4*)&s_u[li]     = *(const float4*)(urow + t8);
        *(float4*)&s_u[li + 4] = *(const float4*)(urow + t8 + 4);
    }
    __syncthreads();

    int t0 = cg * 128;
    int lb = cg * 132;
    const float* pB = BtP + ((size_t)b * LL + t0) * 16 + n;
    const float* pC = CtP + ((size_t)b * LL + t0) * 16 + n;

    // ---- phase 1: per-chunk aggregates; aP in log space
    float h = 0.f, sdu = 0.f;
    float4 du_c = *(float4*)&s_d[lb];
    float4 u_c  = *(float4*)&s_u[lb];
    float B0 = pB[0], B1 = pB[16], B2 = pB[32], B3 = pB[48];
    for (int s = 0; s < 31; ++s) {
        int ln = lb + s * 4 + 4;
        const float* pBn = pB + s * 64 + 64;
        float4 du_n = *(float4*)&s_d[ln];
        float4 u_n  = *(float4*)&s_u[ln];
        float Bn0 = pBn[0], Bn1 = pBn[16], Bn2 = pBn[32], Bn3 = pBn[48];
        float a0 = fexp2(du_c.x * A2), a1 = fexp2(du_c.y * A2);
        float a2 = fexp2(du_c.z * A2), a3 = fexp2(du_c.w * A2);
        h = fmaf(a0, h, (du_c.x * u_c.x) * B0);
        h = fmaf(a1, h, (du_c.y * u_c.y) * B1);
        h = fmaf(a2, h, (du_c.z * u_c.z) * B2);
        h = fmaf(a3, h, (du_c.w * u_c.w) * B3);
        sdu += (du_c.x + du_c.y) + (du_c.z + du_c.w);
        du_c = du_n; u_c = u_n; B0 = Bn0; B1 = Bn1; B2 = Bn2; B3 = Bn3;
    }
    {
        float a0 = fexp2(du_c.x * A2), a1 = fexp2(du_c.y * A2);
        float a2 = fexp2(du_c.z * A2), a3 = fexp2(du_c.w * A2);
        h = fmaf(a0, h, (du_c.x * u_c.x) * B0);
        h = fmaf(a1, h, (du_c.y * u_c.y) * B1);
        h = fmaf(a2, h, (du_c.z * u_c.z) * B2);
        h = fmaf(a3, h, (du_c.w * u_c.w) * B3);
        sdu += (du_c.x + du_c.y) + (du_c.z + du_c.w);
    }
    s_a[cg][n] = fexp2(sdu * A2);
    s_h[cg][n] = h;
    __syncthreads();

    // ---- phase 2: Kogge-Stone scan of 32 chunk aggregates (per n)
    {
        int l = tid & 63, w = tid >> 6;
        int c = l & 31, nn = (w << 1) | (l >> 5);
        float a  = s_a[c][nn];
        float hh = s_h[c][nn];
#pragma unroll
        for (int st = 1; st < 32; st <<= 1) {
            float ap = __shfl_up(a, st, 32);
            float hp = __shfl_up(hh, st, 32);
            bool ok = (c >= st);
            hh = ok ? fmaf(a, hp, hh) : hh;
            a  = ok ? a * ap : a;
        }
        float h0 = __shfl_up(hh, 1, 32);
        if (c == 0) h0 = 0.f;
        s_a[c][nn] = h0;
    }
    __syncthreads();

    // ---- phase 3: recompute with h0; partial-butterfly reduce; lane-t epilogue
    h = s_a[cg][n];
    const int j = n & 3;
    const bool e1 = (j == 1), e2 = (j == 2), e3 = (j == 3);
    du_c = *(float4*)&s_d[lb];
    u_c  = *(float4*)&s_u[lb];
    B0 = pB[0]; B1 = pB[16]; B2 = pB[32]; B3 = pB[48];
    float C0 = pC[0], C1 = pC[16], C2 = pC[32], C3 = pC[48];
    ushort4 z_c = *(const ushort4*)(zrow + t0);
    for (int s = 0; s < 32; ++s) {
        float4 du_n, u_n;
        ushort4 z_n;
        float Bn0, Bn1, Bn2, Bn3, Cn0, Cn1, Cn2, Cn3;
        if (s < 31) {
            int ln = lb + s * 4 + 4;
            const float* pBn = pB + s * 64 + 64;
            const float* pCn = pC + s * 64 + 64;
            du_n = *(float4*)&s_d[ln];
            u_n  = *(float4*)&s_u[ln];
            Bn0 = pBn[0]; Bn1 = pBn[16]; Bn2 = pBn[32]; Bn3 = pBn[48];
            Cn0 = pCn[0]; Cn1 = pCn[16]; Cn2 = pCn[32]; Cn3 = pCn[48];
            z_n = *(const ushort4*)(zrow + t0 + s * 4 + 4);
        }
        float a0 = fexp2(du_c.x * A2), a1 = fexp2(du_c.y * A2);
        float a2 = fexp2(du_c.z * A2), a3 = fexp2(du_c.w * A2);
        h = fmaf(a0, h, (du_c.x * u_c.x) * B0); float p0 = h * C0;
        h = fmaf(a1, h, (du_c.y * u_c.y) * B1); float p1 = h * C1;
        h = fmaf(a2, h, (du_c.z * u_c.z) * B2); float p2 = h * C2;
        h = fmaf(a3, h, (du_c.w * u_c.w) * B3); float p3 = h * C3;
        p0 += __shfl_xor(p0, 1); p0 += __shfl_xor(p0, 2);
        p1 += __shfl_xor(p1, 1); p1 += __shfl_xor(p1, 2);
        p2 += __shfl_xor(p2, 1); p2 += __shfl_xor(p2, 2);
        p3 += __shfl_xor(p3, 1); p3 += __shfl_xor(p3, 2);
        float pj = e3 ? p3 : (e2 ? p2 : (e1 ? p1 : p0));
        pj += __shfl_xor(pj, 4); pj += __shfl_xor(pj, 8);
        float uj = e3 ? u_c.w : (e2 ? u_c.z : (e1 ? u_c.y : u_c.x));
        ushort_t zu = e3 ? z_c.w : (e2 ? z_c.z : (e1 ? z_c.y : z_c.x));
        float yj = fmaf(Dd, uj, pj) * siluf(bf2f(zu));
        if (n < 4)
            ygr[t0 + s * 4 + n] = f2bf(yj);
        du_c = du_n; u_c = u_n; z_c = z_n;
        B0 = Bn0; B1 = Bn1; B2 = Bn2; B3 = Bn3;
        C0 = Cn0; C1 = Cn1; C2 = Cn2; C3 = Cn3;
    }
}

// ---------------- Kernel 6: out_proj via MFMA with LDS transpose of yg[d][t]
__global__ __launch_bounds__(512, 2) void k_outproj(const ushort_t* __restrict__ xzb,
                                                    const ushort_t* __restrict__ Wobf,
                                                    float* __restrict__ out) {
    __shared__ ushort_t s_yg[64][216];
    int tid = threadIdx.x;
    int b = blockIdx.y;
    int l0 = blockIdx.x * 64;
    const ushort_t* ygb = xzb + (size_t)b * 384 * LL;
    {
        int q = tid & 63, o = tid >> 6;
        if (q < 48) {
            uint4 v[4];
#pragma unroll
            for (int jj = 0; jj < 4; ++jj)
                v[jj] = *(const uint4*)(ygb + (size_t)(q * 4 + jj) * LL + l0 + o * 8);
            const ushort_t* vs = (const ushort_t*)v;
#pragma unroll
            for (int j2 = 0; j2 < 8; ++j2) {
                ushort4 pk;
                pk.x = vs[j2]; pk.y = vs[8 + j2]; pk.z = vs[16 + j2]; pk.w = vs[24 + j2];
                *(ushort4*)&s_yg[o * 8 + j2][q * 4] = pk;
            }
        }
    }
    __syncthreads();
    int w = tid >> 6, l = tid & 63;
    int n = l & 15, g = l >> 4;
    int lt = (w >> 1) * 16;
    int c0 = (w & 1) * 48;
    const ushort_t* bp = &s_yg[lt + n][g * 8];
    const ushort_t* ap = Wobf + ((size_t)c0 + n) * 192 + g * 8;
    v4f acc[3];
#pragma unroll
    for (int m = 0; m < 3; ++m) acc[m] = (v4f){0.f, 0.f, 0.f, 0.f};
#pragma unroll
    for (int kk = 0; kk < 6; ++kk) {
        v8s bf = *(const v8s*)(bp + kk * 32);
#pragma unroll
        for (int m = 0; m < 3; ++m) {
            v8s af = *(const v8s*)(ap + m * 16 * 192 + kk * 32);
            acc[m] = __builtin_amdgcn_mfma_f32_16x16x32_bf16(af, bf, acc[m], 0, 0, 0);
        }
    }
    float* ob = out + (size_t)b * 96 * LL + l0 + lt + n;
#pragma unroll
    for (int m = 0; m < 3; ++m)
#pragma unroll
        for (int r = 0; r < 4; ++r)
            ob[(size_t)(c0 + m * 16 + g * 4 + r) * LL] = acc[m][r];
}

extern "C" void kernel_launch(void* const* d_in, const int* in_sizes, int n_in,
                              void* d_out, int out_size, void* d_ws, size_t ws_size,
                              hipStream_t stream) {
    const float* x         = (const float*)d_in[0];
    const float* proj_w    = (const float*)d_in[1];
    const float* dconv_w   = (const float*)d_in[2];
    const float* in_proj_w = (const float*)d_in[3];
    const float* conv1d_w  = (const float*)d_in[4];
    const float* conv1d_b  = (const float*)d_in[5];
    const float* x_proj_w  = (const float*)d_in[6];
    const float* dt_proj_w = (const float*)d_in[7];
    const float* dt_proj_b = (const float*)d_in[8];
    const float* A_log     = (const float*)d_in[9];
    const float* Dp        = (const float*)d_in[10];
    const float* out_proj_w= (const float*)d_in[11];
    float* out = (float*)d_out;
    float* ws  = (float*)d_ws;

    // carve (float units)
    ushort_t* Wbf  = (ushort_t*)ws;                      // 82,944 sh -> 41,472 fl
    ushort_t* Wibf = (ushort_t*)(ws + 41472);            // 36,864 sh -> 18,432 fl
    ushort_t* Wobf = (ushort_t*)(ws + 59904);            // 18,432 sh ->  9,216 fl
    ushort_t* Wxbf = (ushort_t*)(ws + 69120);            //  9,216 sh ->  4,608 fl
    ushort_t* xT   = (ushort_t*)(ws + 73728);            // 1,723,392 sh -> 861,696 fl
    ushort_t* xzb  = (ushort_t*)(ws + 1721856);          // 4*384*4096 bf16 -> 3,145,728 fl
    float* xc   = ws + 4867584;                          // 3,145,728
    float* dtT  = xc + 3145728;                          // 4*6*4096   =    98,304
    float* BtP  = dtT + 98304;                           // 4*4096*16  =   262,144
    float* CtP  = BtP + 262144;                          // 4*4096*16  =   262,144
    ushort_t* xcT = (ushort_t*)(CtP + 262144);           // 4*4096*192 bf16
    // yg[d][t] bf16 aliases xzb lower (xin) half per-batch (dead after conv1d)

    k_prep<<<dim3(840), dim3(256), 0, stream>>>(proj_w, dconv_w, in_proj_w, out_proj_w,
                                                x_proj_w, x, Wbf, Wibf, Wobf, Wxbf, xT);
    k_convin<<<dim3(512), dim3(384), 0, stream>>>(xT, Wbf, Wibf, xzb);
    k_conv1d<<<dim3(256, 3, 4), dim3(256), 0, stream>>>(xzb, conv1d_w, conv1d_b, xc, xcT);
    k_xprojm<<<dim3(64, 4), dim3(256), 0, stream>>>(xcT, Wxbf, dtT, BtP, CtP);
    k_scan<<<dim3(768), dim3(512), 0, stream>>>(dtT, dt_proj_w, dt_proj_b, xc, BtP, CtP,
                                                A_log, Dp, xzb);
    k_outproj<<<dim3(64, 4), dim3(512), 0, stream>>>(xzb, Wobf, out);
}